// Round 3
// baseline (1191.061 us; speedup 1.0000x reference)
//
#include <hip/hip_runtime.h>
#include <hip/hip_bf16.h>

// EGCL (EGNN layer): N=384 nodes, V=32 vectors, H=128 feats, U=256 width.
// E = N*(N-1) = 147072 fully-connected edges. f32 in/out, bf16 MFMA compute.
// Edges grouped by RECEIVER r (s=(r+1+j')%N): segment sums are in-block
// register reductions; [E,256] intermediates never touch HBM.
// R2 changes: LDS 73.7->51.6KB (3 blocks/CU), launch_bounds(256,3) to avoid
// spill-to-scratch (R1 showed 584MB of mystery TCC writes), vec/len
// recomputed from L1 instead of stored, phixb aliased onto dead efb,
// grid 3x384 -> 6x384, repacks fused into one launch.

#define NN 384
#define VV 32
#define HH 128
#define UU 256
#define DE 288           // V + 2H
#define EF_S 296         // LDS row stride for 288-wide buf (+8 pad)
#define U_S 264          // LDS row stride for 256-wide bufs (+8 pad)

typedef __bf16 bf16v8 __attribute__((ext_vector_type(8)));
typedef __bf16 bf16v4 __attribute__((ext_vector_type(4)));
typedef float  f32x4  __attribute__((ext_vector_type(4)));

// ------------- fused weight repack: P[kt][n][kk] = (bf16)W[kt*32+kk][n] ----
// ranges (elements): We1 73728 | We2 65536 | Wx1 65536 | Wx2 65536 | Wxl 8192
__global__ void repack_all(const float* __restrict__ We1, const float* __restrict__ We2,
                           const float* __restrict__ Wx1, const float* __restrict__ Wx2,
                           const float* __restrict__ Wxl,
                           __bf16* __restrict__ we1p, __bf16* __restrict__ we2p,
                           __bf16* __restrict__ wx1p, __bf16* __restrict__ wx2p,
                           __bf16* __restrict__ wxlp) {
    int t = blockIdx.x * 256 + threadIdx.x;
    const float* src; __bf16* dst; int Nout; int idx;
    if (t < 73728)       { src = We1; dst = we1p; Nout = 256; idx = t; }
    else if (t < 139264) { src = We2; dst = we2p; Nout = 256; idx = t - 73728; }
    else if (t < 204800) { src = Wx1; dst = wx1p; Nout = 256; idx = t - 139264; }
    else if (t < 270336) { src = Wx2; dst = wx2p; Nout = 256; idx = t - 204800; }
    else if (t < 278528) { src = Wxl; dst = wxlp; Nout = 32;  idx = t - 270336; }
    else return;
    int kt  = idx / (Nout * 32);
    int rem = idx - kt * Nout * 32;
    int n   = rem >> 5;
    int kk  = rem & 31;
    dst[idx] = (__bf16)src[(kt * 32 + kk) * Nout + n];
}

// ---- one 32x256 GEMM layer: Y = silu(scale * X @ W), all waves cooperate ---
__device__ __forceinline__ void gemm256(const __bf16* X, int xs,
                                        const __bf16* __restrict__ P, int KT,
                                        __bf16* Y, int ys, float scale,
                                        int wave, int col, int q) {
    f32x4 acc[2][4] = {};
    const __bf16* xr0 = X + col * xs + q * 8;
    const __bf16* xr1 = X + (16 + col) * xs + q * 8;
    const __bf16* pb  = P + (wave * 64 + col) * 32 + q * 8;
    for (int kt = 0; kt < KT; ++kt) {
        bf16v8 a0 = *(const bf16v8*)(xr0 + kt * 32);
        bf16v8 a1 = *(const bf16v8*)(xr1 + kt * 32);
#pragma unroll
        for (int nt = 0; nt < 4; ++nt) {
            bf16v8 b = *(const bf16v8*)(pb + kt * (UU * 32) + nt * (16 * 32));
            acc[0][nt] = __builtin_amdgcn_mfma_f32_16x16x32_bf16(a0, b, acc[0][nt], 0, 0, 0);
            acc[1][nt] = __builtin_amdgcn_mfma_f32_16x16x32_bf16(a1, b, acc[1][nt], 0, 0, 0);
        }
    }
#pragma unroll
    for (int mt = 0; mt < 2; ++mt)
#pragma unroll
        for (int nt = 0; nt < 4; ++nt)
#pragma unroll
            for (int i = 0; i < 4; ++i) {
                float v = acc[mt][nt][i] * scale;
                v = v / (1.f + __expf(-v));            // silu
                Y[(mt * 16 + q * 4 + i) * ys + wave * 64 + nt * 16 + col] = (__bf16)v;
            }
}

// --------------------------- fused edge kernel -----------------------------
__global__ __launch_bounds__(256, 3)
void edge_kernel(const float* __restrict__ nv, const float* __restrict__ nf,
                 const __bf16* __restrict__ we1p, const __bf16* __restrict__ we2p,
                 const __bf16* __restrict__ wx1p, const __bf16* __restrict__ wx2p,
                 const __bf16* __restrict__ wxlp, const float* __restrict__ bxl,
                 const float* __restrict__ winf,
                 float* __restrict__ shiftws, float* __restrict__ miws) {
    __shared__ __align__(16) __bf16 efb[32 * EF_S];   // ef / t1 / (phixb,gate scratch alias)
    __shared__ __align__(16) __bf16 h1b[32 * U_S];    // h1 / t2
    __shared__ __align__(16) __bf16 mb [32 * U_S];    // m_ij (kept to tile end)
    __shared__ float  gateb[32];
    float* gs    = (float*)efb;          // 256-float gate partial scratch (ef dead)
    float* phixb = (float*)efb;          // 1024-float phi_x buffer (t1 dead)

    const int tid  = threadIdx.x;
    const int wave = tid >> 6;
    const int lane = tid & 63;
    const int col  = lane & 15;
    const int q    = lane >> 4;
    const int r     = blockIdx.y;
    const int chunk = blockIdx.x;

    float macc = 0.f;                    // per-thread m_i[r][tid] accumulator
    float sreg = 0.f;                    // per-thread shifts[r][v][c] (tid<96)
    const int sv = tid / 3, sc = tid - sv * 3;

    for (int t = 0; t < 2; ++t) {
        const int jbase = chunk * 64 + t * 32;
        __syncthreads();   // previous tile's reductions done before overwrite

        // ---- stage edge features: [len2 | nf[s] | nf[r]] ----
        for (int p = tid; p < 1024; p += 256) {
            int i = p >> 5, v = p & 31;
            int s = r + 1 + jbase + i; if (s >= NN) s -= NN;
            const float* pr = nv + (r * 32 + v) * 3;
            const float* ps = nv + (s * 32 + v) * 3;
            float d0 = pr[0] - ps[0];
            float d1 = pr[1] - ps[1];
            float d2 = pr[2] - ps[2];
            efb[i * EF_S + v] = (__bf16)(d0 * d0 + d1 * d1 + d2 * d2);
        }
        for (int p = tid; p < 1024; p += 256) {
            int i = p >> 5, hc = (p & 31) << 2;
            int s = r + 1 + jbase + i; if (s >= NN) s -= NN;
            float4 fs = *(const float4*)(nf + s * HH + hc);
            float4 fr = *(const float4*)(nf + r * HH + hc);
            bf16v4 bs = { (__bf16)fs.x, (__bf16)fs.y, (__bf16)fs.z, (__bf16)fs.w };
            bf16v4 br = { (__bf16)fr.x, (__bf16)fr.y, (__bf16)fr.z, (__bf16)fr.w };
            *(bf16v4*)&efb[i * EF_S + 32 + hc]  = bs;
            *(bf16v4*)&efb[i * EF_S + 160 + hc] = br;
        }
        __syncthreads();

        // ---- h1 = silu(ef @ We1 / sqrt(288)) ----
        gemm256(efb, EF_S, we1p, 9, h1b, U_S, 0.05892556509887896f, wave, col, q);
        __syncthreads();
        // ---- m = silu(h1 @ We2 / 16) ----     (ef now dead)
        gemm256(h1b, U_S, we2p, 8, mb, U_S, 0.0625f, wave, col, q);
        __syncthreads();

        // ---- gate e = sigmoid(m @ Winf / 16); partials in efb-alias scratch
        {
            int i = tid >> 3, kp = (tid & 7) * 32;
            float a = 0.f;
            for (int k = 0; k < 32; ++k)
                a += (float)mb[i * U_S + kp + k] * winf[kp + k];
            gs[tid] = a;
        }
        __syncthreads();
        if (tid < 32) {
            float a = 0.f;
            for (int p8 = 0; p8 < 8; ++p8) a += gs[tid * 8 + p8];
            gateb[tid] = (jbase + tid == NN - 1) ? 0.f      // self-edge pad
                                                 : 1.f / (1.f + __expf(-a * 0.0625f));
        }
        __syncthreads();   // gate scratch read complete before t1 overwrites efb

        // ---- t1 = silu(m @ Wx1 / 16) into efb; t2 = silu(t1 @ Wx2 / 16) ----
        gemm256(mb, U_S, wx1p, 8, efb, EF_S, 0.0625f, wave, col, q);
        __syncthreads();
        gemm256(efb, EF_S, wx2p, 8, h1b, U_S, 0.0625f, wave, col, q);
        __syncthreads();

        // ---- phi_x = t2 @ Wxl + bxl  (into efb-alias phixb; t1 dead) ----
        {
            int mt = wave >> 1, nt = wave & 1;
            f32x4 acc = {0.f, 0.f, 0.f, 0.f};
            const __bf16* xr = h1b + (mt * 16 + col) * U_S + q * 8;
#pragma unroll
            for (int kt = 0; kt < 8; ++kt) {
                bf16v8 a = *(const bf16v8*)(xr + kt * 32);
                bf16v8 b = *(const bf16v8*)(wxlp + (kt * 32 + nt * 16 + col) * 32 + q * 8);
                acc = __builtin_amdgcn_mfma_f32_16x16x32_bf16(a, b, acc, 0, 0, 0);
            }
            float bias = bxl[nt * 16 + col];
#pragma unroll
            for (int i = 0; i < 4; ++i)
                phixb[(mt * 16 + q * 4 + i) * 32 + nt * 16 + col] = acc[i] + bias;
        }
        __syncthreads();

        // ---- accumulate shifts; vec/len recomputed from L1-cached nv ----
        if (tid < 96) {
            float r0 = nv[(r * 32 + sv) * 3 + 0];
            float r1 = nv[(r * 32 + sv) * 3 + 1];
            float r2 = nv[(r * 32 + sv) * 3 + 2];
            for (int i = 0; i < 32; ++i) {
                int s = r + 1 + jbase + i; if (s >= NN) s -= NN;
                const float* ps = nv + (s * 32 + sv) * 3;
                float d0 = r0 - ps[0], d1 = r1 - ps[1], d2 = r2 - ps[2];
                float len = sqrtf(fmaxf(d0 * d0 + d1 * d1 + d2 * d2, 1e-20f));
                float d = (sc == 0) ? d0 : ((sc == 1) ? d1 : d2);
                sreg += phixb[i * 32 + sv] * d / (1.f + len);
            }
        }
        // ---- accumulate m_i (gate zeroed on self-edge) ----
        for (int i = 0; i < 32; ++i)
            macc += (float)mb[i * U_S + tid] * gateb[i];
    }

    atomicAdd(&miws[r * UU + tid], macc);
    if (tid < 96) atomicAdd(&shiftws[r * 96 + tid], sreg);
}

// --------------------------- node-level epilogue ---------------------------
__global__ __launch_bounds__(256, 2)
void node_kernel(const float* __restrict__ nv, const float* __restrict__ nf,
                 const float* __restrict__ Wh1, const float* __restrict__ Wh2,
                 const float* __restrict__ Whl,
                 const float* __restrict__ shiftws, const float* __restrict__ miws,
                 float* __restrict__ out) {
    __shared__ float xs[384];
    __shared__ float h1[256];
    __shared__ float h2[256];
    const int n = blockIdx.x, tid = threadIdx.x;

    xs[tid] = miws[n * UU + tid];
    if (tid < 128) xs[256 + tid] = nf[n * HH + tid];
    if (tid < 96)  // vectors_out = nv + shifts/(N-1)
        out[n * 96 + tid] = nv[n * 96 + tid] + shiftws[n * 96 + tid] * (1.f / 383.f);
    __syncthreads();

    float a = 0.f;
    for (int k = 0; k < 384; ++k) a += xs[k] * Wh1[k * 256 + tid];
    a *= 0.05103103630798288f;              // 1/sqrt(384)
    h1[tid] = a / (1.f + __expf(-a));
    __syncthreads();

    a = 0.f;
    for (int k = 0; k < 256; ++k) a += h1[k] * Wh2[k * 256 + tid];
    a *= 0.0625f;
    h2[tid] = a / (1.f + __expf(-a));
    __syncthreads();

    if (tid < 128) {
        a = 0.f;
        for (int k = 0; k < 256; ++k) a += h2[k] * Whl[k * 128 + tid];
        out[NN * 96 + n * HH + tid] = a * 0.0625f + nf[n * HH + tid];
    }
}

// ------------------------------- launcher ----------------------------------
extern "C" void kernel_launch(void* const* d_in, const int* in_sizes, int n_in,
                              void* d_out, int out_size, void* d_ws, size_t ws_size,
                              hipStream_t stream) {
    const float* nv   = (const float*)d_in[0];
    const float* nf   = (const float*)d_in[1];
    const float* We1  = (const float*)d_in[2];
    const float* We2  = (const float*)d_in[3];
    const float* Wx1  = (const float*)d_in[4];
    const float* Wx2  = (const float*)d_in[5];
    const float* Wxl  = (const float*)d_in[6];
    const float* bxl  = (const float*)d_in[7];
    const float* Winf = (const float*)d_in[8];
    const float* Wh1  = (const float*)d_in[9];
    const float* Wh2  = (const float*)d_in[10];
    const float* Whl  = (const float*)d_in[11];
    float* out = (float*)d_out;

    char* ws = (char*)d_ws;
    float*  shiftws = (float*)ws;                       // 384*96*4  = 147456 B
    float*  miws    = (float*)(ws + 147456);            // 384*256*4 = 393216 B
    __bf16* we1p    = (__bf16*)(ws + 540672);           // 9*256*32*2 = 147456 B
    __bf16* we2p    = (__bf16*)(ws + 688128);           // 8*256*32*2 = 131072 B
    __bf16* wx1p    = (__bf16*)(ws + 819200);
    __bf16* wx2p    = (__bf16*)(ws + 950272);
    __bf16* wxlp    = (__bf16*)(ws + 1081344);          // 8*32*32*2 = 16384 B

    hipMemsetAsync(d_ws, 0, 540672, stream);            // zero accumulators

    repack_all<<<dim3(1088), 256, 0, stream>>>(We1, We2, Wx1, Wx2, Wxl,
                                               we1p, we2p, wx1p, wx2p, wxlp);

    edge_kernel<<<dim3(6, NN), 256, 0, stream>>>(nv, nf, we1p, we2p, wx1p, wx2p,
                                                 wxlp, bxl, Winf, shiftws, miws);
    node_kernel<<<dim3(NN), 256, 0, stream>>>(nv, nf, Wh1, Wh2, Whl,
                                              shiftws, miws, out);
}

// Round 4
// 339.745 us; speedup vs baseline: 3.5058x; 3.5058x over previous
//
#include <hip/hip_runtime.h>
#include <hip/hip_bf16.h>

// EGCL (EGNN layer): N=384 nodes, V=32 vectors, H=128 feats, U=256 width.
// E = N*(N-1) = 147072 fully-connected edges. f32 in/out, bf16 MFMA compute.
// Edges grouped by RECEIVER r (s=(r+1+j')%N): segment sums are in-block
// reductions; [E,256] intermediates never touch HBM.
// R4: M=128 edges/block (was 32) to amortize weight fetches 4x (R1/R3 showed
// FETCH ~= 50% of weight request volume -> reuse-distance thrash in L2).
// 512 threads, 2 ping-pong LDS activation buffers; m dies early by doing the
// gate + m_i reduction right after m, before the phi_x chain reuses buffers.

#define NN 384
#define VV 32
#define HH 128
#define UU 256
#define MM 128           // edges per block
#define AS 296           // A-buffer row stride (288-wide ef, +8 pad)
#define BS 264           // B-buffer row stride (256-wide, +8 pad)

typedef __bf16 bf16v8 __attribute__((ext_vector_type(8)));
typedef __bf16 bf16v4 __attribute__((ext_vector_type(4)));
typedef float  f32x4  __attribute__((ext_vector_type(4)));

// ------------- fused weight repack: P[kt][n][kk] = (bf16)W[kt*32+kk][n] ----
__global__ void repack_all(const float* __restrict__ We1, const float* __restrict__ We2,
                           const float* __restrict__ Wx1, const float* __restrict__ Wx2,
                           const float* __restrict__ Wxl,
                           __bf16* __restrict__ we1p, __bf16* __restrict__ we2p,
                           __bf16* __restrict__ wx1p, __bf16* __restrict__ wx2p,
                           __bf16* __restrict__ wxlp) {
    int t = blockIdx.x * 256 + threadIdx.x;
    const float* src; __bf16* dst; int Nout; int idx;
    if (t < 73728)       { src = We1; dst = we1p; Nout = 256; idx = t; }
    else if (t < 139264) { src = We2; dst = we2p; Nout = 256; idx = t - 73728; }
    else if (t < 204800) { src = Wx1; dst = wx1p; Nout = 256; idx = t - 139264; }
    else if (t < 270336) { src = Wx2; dst = wx2p; Nout = 256; idx = t - 204800; }
    else if (t < 278528) { src = Wxl; dst = wxlp; Nout = 32;  idx = t - 270336; }
    else return;
    int kt  = idx / (Nout * 32);
    int rem = idx - kt * Nout * 32;
    int n   = rem >> 5;
    int kk  = rem & 31;
    dst[idx] = (__bf16)src[(kt * 32 + kk) * Nout + n];
}

// ---- one 128x256 GEMM layer: Y = silu(scale * X @ W), 8 waves cooperate ---
// wave = (mhalf 0..1)*4 + (colq 0..3): rows mhalf*64+mt*16, cols colq*64+nt*16
template <int KT>
__device__ __forceinline__ void gemm512(const __bf16* X, int xs,
                                        const __bf16* __restrict__ P,
                                        __bf16* Y, int ys, float scale,
                                        int wave, int col, int q) {
    const int mhalf = wave >> 2, colq = wave & 3;
    f32x4 acc[4][4] = {};
    const __bf16* xr = X + (mhalf * 64 + col) * xs + q * 8;
    const __bf16* pb = P + (colq * 64 + col) * 32 + q * 8;
    for (int kt = 0; kt < KT; ++kt) {
        bf16v8 a[4], b[4];
#pragma unroll
        for (int mt = 0; mt < 4; ++mt)
            a[mt] = *(const bf16v8*)(xr + mt * 16 * xs + kt * 32);
#pragma unroll
        for (int nt = 0; nt < 4; ++nt)
            b[nt] = *(const bf16v8*)(pb + kt * (UU * 32) + nt * (16 * 32));
#pragma unroll
        for (int mt = 0; mt < 4; ++mt)
#pragma unroll
            for (int nt = 0; nt < 4; ++nt)
                acc[mt][nt] = __builtin_amdgcn_mfma_f32_16x16x32_bf16(a[mt], b[nt], acc[mt][nt], 0, 0, 0);
    }
#pragma unroll
    for (int mt = 0; mt < 4; ++mt)
#pragma unroll
        for (int nt = 0; nt < 4; ++nt)
#pragma unroll
            for (int i = 0; i < 4; ++i) {
                float v = acc[mt][nt][i] * scale;
                v = v / (1.f + __expf(-v));            // silu
                Y[(mhalf * 64 + mt * 16 + q * 4 + i) * ys + colq * 64 + nt * 16 + col] = (__bf16)v;
            }
}

// --------------------------- fused edge kernel -----------------------------
__global__ __launch_bounds__(512, 2)
void edge_kernel(const float* __restrict__ nv, const float* __restrict__ nf,
                 const __bf16* __restrict__ we1p, const __bf16* __restrict__ we2p,
                 const __bf16* __restrict__ wx1p, const __bf16* __restrict__ wx2p,
                 const __bf16* __restrict__ wxlp, const float* __restrict__ bxl,
                 const float* __restrict__ winf,
                 float* __restrict__ shiftws, float* __restrict__ miws) {
    __shared__ __align__(16) __bf16 Ab[MM * AS];   // ef -> m -> t2 -> spart
    __shared__ __align__(16) __bf16 Bb[MM * BS];   // h1 -> scratch -> t1 -> phix(f32)
    __shared__ float gateb[MM];

    float* Bf    = (float*)Bb;    // scratch / phix views
    float* Af    = (float*)Ab;    // spart view

    const int tid  = threadIdx.x;
    const int wave = tid >> 6;
    const int lane = tid & 63;
    const int col  = lane & 15;
    const int q    = lane >> 4;
    const int r    = blockIdx.y;
    const int e0   = blockIdx.x * MM;   // edge base within r's 383(+1 pad)

    // ---- stage edge features: [len2 | nf[s] | nf[r]] into A ----
    for (int p = tid; p < MM * 32; p += 512) {
        int i = p >> 5, v = p & 31;
        int s = r + 1 + e0 + i; if (s >= NN) s -= NN;
        const float* pr = nv + (r * 32 + v) * 3;
        const float* ps = nv + (s * 32 + v) * 3;
        float d0 = pr[0] - ps[0];
        float d1 = pr[1] - ps[1];
        float d2 = pr[2] - ps[2];
        Ab[i * AS + v] = (__bf16)(d0 * d0 + d1 * d1 + d2 * d2);
    }
    for (int p = tid; p < MM * 32; p += 512) {
        int i = p >> 5, hc = (p & 31) << 2;
        int s = r + 1 + e0 + i; if (s >= NN) s -= NN;
        float4 fs = *(const float4*)(nf + s * HH + hc);
        float4 fr = *(const float4*)(nf + r * HH + hc);
        bf16v4 bs = { (__bf16)fs.x, (__bf16)fs.y, (__bf16)fs.z, (__bf16)fs.w };
        bf16v4 br = { (__bf16)fr.x, (__bf16)fr.y, (__bf16)fr.z, (__bf16)fr.w };
        *(bf16v4*)&Ab[i * AS + 32 + hc]  = bs;
        *(bf16v4*)&Ab[i * AS + 160 + hc] = br;
    }
    __syncthreads();

    // ---- h1 = silu(ef @ We1 / sqrt(288)) : A -> B ----
    gemm512<9>(Ab, AS, we1p, Bb, BS, 0.05892556509887896f, wave, col, q);
    __syncthreads();
    // ---- m = silu(h1 @ We2 / 16) : B -> A ----
    gemm512<8>(Bb, BS, we2p, Ab, AS, 0.0625f, wave, col, q);
    __syncthreads();

    // ---- gate e = sigmoid(m @ Winf / 16); partials in B scratch ----
    {
        int i = tid >> 2, kq = (tid & 3) * 64;
        float g = 0.f;
        for (int k = 0; k < 64; ++k)
            g += (float)Ab[i * AS + kq + k] * winf[kq + k];
        Bf[tid] = g;
    }
    __syncthreads();
    if (tid < MM) {
        float g = Bf[tid * 4] + Bf[tid * 4 + 1] + Bf[tid * 4 + 2] + Bf[tid * 4 + 3];
        gateb[tid] = (e0 + tid == NN - 1) ? 0.f     // self-edge pad
                                          : 1.f / (1.f + __expf(-g * 0.0625f));
    }
    __syncthreads();

    // ---- m_i partial reduction: col=tid&255, half=tid>>8 ----
    {
        int c = tid & 255, ih = (tid >> 8) * 64;
        float mp = 0.f;
        for (int i = 0; i < 64; ++i)
            mp += (float)Ab[(ih + i) * AS + c] * gateb[ih + i];
        Bf[tid] = mp;
    }
    __syncthreads();
    if (tid < 256) atomicAdd(&miws[r * UU + tid], Bf[tid] + Bf[256 + tid]);
    __syncthreads();

    // ---- t1 = silu(m @ Wx1 / 16) : A -> B ; t2 = silu(t1 @ Wx2 /16): B -> A
    gemm512<8>(Ab, AS, wx1p, Bb, BS, 0.0625f, wave, col, q);
    __syncthreads();
    gemm512<8>(Bb, BS, wx2p, Ab, AS, 0.0625f, wave, col, q);
    __syncthreads();

    // ---- phi_x = t2 @ Wxl + bxl : A -> Bf (f32, 128x32) ----
    {
        f32x4 acc[2] = {};
        const __bf16* xr = Ab + (wave * 16 + col) * AS + q * 8;
#pragma unroll
        for (int kt = 0; kt < 8; ++kt) {
            bf16v8 a = *(const bf16v8*)(xr + kt * 32);
#pragma unroll
            for (int nt = 0; nt < 2; ++nt) {
                bf16v8 b = *(const bf16v8*)(wxlp + (kt * 32 + nt * 16 + col) * 32 + q * 8);
                acc[nt] = __builtin_amdgcn_mfma_f32_16x16x32_bf16(a, b, acc[nt], 0, 0, 0);
            }
        }
#pragma unroll
        for (int nt = 0; nt < 2; ++nt) {
            float bias = bxl[nt * 16 + col];
#pragma unroll
            for (int i = 0; i < 4; ++i)
                Bf[(wave * 16 + q * 4 + i) * 32 + nt * 16 + col] = acc[nt][i] + bias;
        }
    }
    __syncthreads();

    // ---- shift partials: tid<384 -> (quarter, sv, sc); vec recomputed ----
    if (tid < 384) {
        int qd = tid / 96, rem = tid % 96;
        int sv = rem / 3, sc = rem - sv * 3;
        float r0 = nv[(r * 32 + sv) * 3 + 0];
        float r1 = nv[(r * 32 + sv) * 3 + 1];
        float r2 = nv[(r * 32 + sv) * 3 + 2];
        float sp = 0.f;
        for (int i = qd * 32; i < qd * 32 + 32; ++i) {
            int s = r + 1 + e0 + i; if (s >= NN) s -= NN;
            const float* ps = nv + (s * 32 + sv) * 3;
            float d0 = r0 - ps[0], d1 = r1 - ps[1], d2 = r2 - ps[2];
            float len = sqrtf(fmaxf(d0 * d0 + d1 * d1 + d2 * d2, 1e-20f));
            float d = (sc == 0) ? d0 : ((sc == 1) ? d1 : d2);
            sp += Bf[i * 32 + sv] * d / (1.f + len);
        }
        Af[qd * 96 + rem] = sp;
    }
    __syncthreads();
    if (tid < 96)
        atomicAdd(&shiftws[r * 96 + tid],
                  Af[tid] + Af[96 + tid] + Af[192 + tid] + Af[288 + tid]);
}

// --------------------------- node-level epilogue ---------------------------
__global__ __launch_bounds__(256, 2)
void node_kernel(const float* __restrict__ nv, const float* __restrict__ nf,
                 const float* __restrict__ Wh1, const float* __restrict__ Wh2,
                 const float* __restrict__ Whl,
                 const float* __restrict__ shiftws, const float* __restrict__ miws,
                 float* __restrict__ out) {
    __shared__ float xs[384];
    __shared__ float h1[256];
    __shared__ float h2[256];
    const int n = blockIdx.x, tid = threadIdx.x;

    xs[tid] = miws[n * UU + tid];
    if (tid < 128) xs[256 + tid] = nf[n * HH + tid];
    if (tid < 96)  // vectors_out = nv + shifts/(N-1)
        out[n * 96 + tid] = nv[n * 96 + tid] + shiftws[n * 96 + tid] * (1.f / 383.f);
    __syncthreads();

    float a = 0.f;
    for (int k = 0; k < 384; ++k) a += xs[k] * Wh1[k * 256 + tid];
    a *= 0.05103103630798288f;              // 1/sqrt(384)
    h1[tid] = a / (1.f + __expf(-a));
    __syncthreads();

    a = 0.f;
    for (int k = 0; k < 256; ++k) a += h1[k] * Wh2[k * 256 + tid];
    a *= 0.0625f;
    h2[tid] = a / (1.f + __expf(-a));
    __syncthreads();

    if (tid < 128) {
        a = 0.f;
        for (int k = 0; k < 256; ++k) a += h2[k] * Whl[k * 128 + tid];
        out[NN * 96 + n * HH + tid] = a * 0.0625f + nf[n * HH + tid];
    }
}

// ------------------------------- launcher ----------------------------------
extern "C" void kernel_launch(void* const* d_in, const int* in_sizes, int n_in,
                              void* d_out, int out_size, void* d_ws, size_t ws_size,
                              hipStream_t stream) {
    const float* nv   = (const float*)d_in[0];
    const float* nf   = (const float*)d_in[1];
    const float* We1  = (const float*)d_in[2];
    const float* We2  = (const float*)d_in[3];
    const float* Wx1  = (const float*)d_in[4];
    const float* Wx2  = (const float*)d_in[5];
    const float* Wxl  = (const float*)d_in[6];
    const float* bxl  = (const float*)d_in[7];
    const float* Winf = (const float*)d_in[8];
    const float* Wh1  = (const float*)d_in[9];
    const float* Wh2  = (const float*)d_in[10];
    const float* Whl  = (const float*)d_in[11];
    float* out = (float*)d_out;

    char* ws = (char*)d_ws;
    float*  shiftws = (float*)ws;                       // 384*96*4  = 147456 B
    float*  miws    = (float*)(ws + 147456);            // 384*256*4 = 393216 B
    __bf16* we1p    = (__bf16*)(ws + 540672);           // 9*256*32*2 = 147456 B
    __bf16* we2p    = (__bf16*)(ws + 688128);           // 8*256*32*2 = 131072 B
    __bf16* wx1p    = (__bf16*)(ws + 819200);
    __bf16* wx2p    = (__bf16*)(ws + 950272);
    __bf16* wxlp    = (__bf16*)(ws + 1081344);          // 8*32*32*2 = 16384 B

    hipMemsetAsync(d_ws, 0, 540672, stream);            // zero accumulators

    repack_all<<<dim3(1088), 256, 0, stream>>>(We1, We2, Wx1, Wx2, Wxl,
                                               we1p, we2p, wx1p, wx2p, wxlp);

    edge_kernel<<<dim3(3, NN), 512, 0, stream>>>(nv, nf, we1p, we2p, wx1p, wx2p,
                                                 wxlp, bxl, Winf, shiftws, miws);
    node_kernel<<<dim3(NN), 256, 0, stream>>>(nv, nf, Wh1, Wh2, Whl,
                                              shiftws, miws, out);
}

// Round 5
// 312.335 us; speedup vs baseline: 3.8134x; 1.0878x over previous
//
#include <hip/hip_runtime.h>
#include <hip/hip_bf16.h>

// EGCL (EGNN layer): N=384 nodes, V=32 vectors, H=128 feats, U=256 width.
// E = N*(N-1) = 147072 fully-connected edges. f32 in/out, bf16 MFMA compute.
// Edges grouped by RECEIVER r (s=(r+1+j')%N): segment sums are in-block
// reductions; [E,256] intermediates never touch HBM.
// R5: M=64 edges/block (LDS 140->72KB) => 2 blocks/CU for cross-block
// latency overlap (R4 had 1 block/CU: every syncthreads was a full drain).
// Atomics+memset removed: per-(r,chunk) partial outputs, node_kernel sums.

#define NN 384
#define VV 32
#define HH 128
#define UU 256
#define MM 64            // edges per block
#define NCHUNK 6         // 6*64 = 384 = 383 edges + 1 pad
#define AS 296           // A-buffer row stride (288-wide ef, +8 pad)
#define BS 264           // B-buffer row stride (256-wide, +8 pad)

typedef __bf16 bf16v8 __attribute__((ext_vector_type(8)));
typedef __bf16 bf16v4 __attribute__((ext_vector_type(4)));
typedef float  f32x4  __attribute__((ext_vector_type(4)));

// ------------- fused weight repack: P[kt][n][kk] = (bf16)W[kt*32+kk][n] ----
__global__ void repack_all(const float* __restrict__ We1, const float* __restrict__ We2,
                           const float* __restrict__ Wx1, const float* __restrict__ Wx2,
                           const float* __restrict__ Wxl,
                           __bf16* __restrict__ we1p, __bf16* __restrict__ we2p,
                           __bf16* __restrict__ wx1p, __bf16* __restrict__ wx2p,
                           __bf16* __restrict__ wxlp) {
    int t = blockIdx.x * 256 + threadIdx.x;
    const float* src; __bf16* dst; int Nout; int idx;
    if (t < 73728)       { src = We1; dst = we1p; Nout = 256; idx = t; }
    else if (t < 139264) { src = We2; dst = we2p; Nout = 256; idx = t - 73728; }
    else if (t < 204800) { src = Wx1; dst = wx1p; Nout = 256; idx = t - 139264; }
    else if (t < 270336) { src = Wx2; dst = wx2p; Nout = 256; idx = t - 204800; }
    else if (t < 278528) { src = Wxl; dst = wxlp; Nout = 32;  idx = t - 270336; }
    else return;
    int kt  = idx / (Nout * 32);
    int rem = idx - kt * Nout * 32;
    int n   = rem >> 5;
    int kk  = rem & 31;
    dst[idx] = (__bf16)src[(kt * 32 + kk) * Nout + n];
}

// ---- one 64x256 GEMM layer: Y = silu(scale * X @ W), 8 waves cooperate ----
// wave = (mh 0..1)*4 + (cq 0..3): rows mh*32+mt*16 (mt<2), cols cq*64+nt*16
template <int KT>
__device__ __forceinline__ void gemm64(const __bf16* X, int xs,
                                       const __bf16* __restrict__ P,
                                       __bf16* Y, int ys, float scale,
                                       int wave, int col, int q) {
    const int mh = wave >> 2, cq = wave & 3;
    f32x4 acc[2][4] = {};
    const __bf16* xr = X + (mh * 32 + col) * xs + q * 8;
    const __bf16* pb = P + (cq * 64 + col) * 32 + q * 8;
#pragma unroll
    for (int kt = 0; kt < KT; ++kt) {
        bf16v8 a[2], b[4];
#pragma unroll
        for (int mt = 0; mt < 2; ++mt)
            a[mt] = *(const bf16v8*)(xr + mt * 16 * xs + kt * 32);
#pragma unroll
        for (int nt = 0; nt < 4; ++nt)
            b[nt] = *(const bf16v8*)(pb + kt * (UU * 32) + nt * (16 * 32));
#pragma unroll
        for (int mt = 0; mt < 2; ++mt)
#pragma unroll
            for (int nt = 0; nt < 4; ++nt)
                acc[mt][nt] = __builtin_amdgcn_mfma_f32_16x16x32_bf16(a[mt], b[nt], acc[mt][nt], 0, 0, 0);
    }
#pragma unroll
    for (int mt = 0; mt < 2; ++mt)
#pragma unroll
        for (int nt = 0; nt < 4; ++nt)
#pragma unroll
            for (int i = 0; i < 4; ++i) {
                float v = acc[mt][nt][i] * scale;
                v = v / (1.f + __expf(-v));            // silu
                Y[(mh * 32 + mt * 16 + q * 4 + i) * ys + cq * 64 + nt * 16 + col] = (__bf16)v;
            }
}

// --------------------------- fused edge kernel -----------------------------
__global__ __launch_bounds__(512, 4)
void edge_kernel(const float* __restrict__ nv, const float* __restrict__ nf,
                 const __bf16* __restrict__ we1p, const __bf16* __restrict__ we2p,
                 const __bf16* __restrict__ wx1p, const __bf16* __restrict__ wx2p,
                 const __bf16* __restrict__ wxlp, const float* __restrict__ bxl,
                 const float* __restrict__ winf,
                 float* __restrict__ shiftp, float* __restrict__ mip) {
    __shared__ __align__(16) __bf16 Ab[MM * AS];   // ef -> m -> t2 -> spart
    __shared__ __align__(16) __bf16 Bb[MM * BS];   // h1 -> scratch -> t1 -> phix(f32)
    __shared__ float gateb[MM];

    float* Bf = (float*)Bb;    // scratch / phix views
    float* Af = (float*)Ab;    // shift-partial view

    const int tid  = threadIdx.x;
    const int wave = tid >> 6;
    const int lane = tid & 63;
    const int col  = lane & 15;
    const int q    = lane >> 4;
    const int r     = blockIdx.y;
    const int chunk = blockIdx.x;
    const int e0    = chunk * MM;      // edge base within r's 383(+1 pad)

    // ---- stage edge features: [len2 | nf[s] | nf[r]] into A ----
    for (int p = tid; p < MM * 32; p += 512) {
        int i = p >> 5, v = p & 31;
        int s = r + 1 + e0 + i; if (s >= NN) s -= NN;
        const float* pr = nv + (r * 32 + v) * 3;
        const float* ps = nv + (s * 32 + v) * 3;
        float d0 = pr[0] - ps[0];
        float d1 = pr[1] - ps[1];
        float d2 = pr[2] - ps[2];
        Ab[i * AS + v] = (__bf16)(d0 * d0 + d1 * d1 + d2 * d2);
    }
    for (int p = tid; p < MM * 32; p += 512) {
        int i = p >> 5, hc = (p & 31) << 2;
        int s = r + 1 + e0 + i; if (s >= NN) s -= NN;
        float4 fs = *(const float4*)(nf + s * HH + hc);
        float4 fr = *(const float4*)(nf + r * HH + hc);
        bf16v4 bs = { (__bf16)fs.x, (__bf16)fs.y, (__bf16)fs.z, (__bf16)fs.w };
        bf16v4 br = { (__bf16)fr.x, (__bf16)fr.y, (__bf16)fr.z, (__bf16)fr.w };
        *(bf16v4*)&Ab[i * AS + 32 + hc]  = bs;
        *(bf16v4*)&Ab[i * AS + 160 + hc] = br;
    }
    __syncthreads();

    // ---- h1 = silu(ef @ We1 / sqrt(288)) : A -> B ----
    gemm64<9>(Ab, AS, we1p, Bb, BS, 0.05892556509887896f, wave, col, q);
    __syncthreads();
    // ---- m = silu(h1 @ We2 / 16) : B -> A ----
    gemm64<8>(Bb, BS, we2p, Ab, AS, 0.0625f, wave, col, q);
    __syncthreads();

    // ---- gate e = sigmoid(m @ Winf / 16); partials in B scratch ----
    {
        int i = tid >> 3, kq = (tid & 7) * 32;
        float g = 0.f;
        for (int k = 0; k < 32; ++k)
            g += (float)Ab[i * AS + kq + k] * winf[kq + k];
        Bf[tid] = g;
    }
    __syncthreads();
    if (tid < MM) {
        float g = 0.f;
        for (int p8 = 0; p8 < 8; ++p8) g += Bf[tid * 8 + p8];
        gateb[tid] = (e0 + tid == NN - 1) ? 0.f     // self-edge pad
                                          : 1.f / (1.f + __expf(-g * 0.0625f));
    }
    __syncthreads();

    // ---- m_i partials: col=tid&255, half=tid>>8 (32 edges each) ----
    {
        int c = tid & 255, ih = (tid >> 8) * 32;
        float mp = 0.f;
        for (int i = 0; i < 32; ++i)
            mp += (float)Ab[(ih + i) * AS + c] * gateb[ih + i];
        Bf[tid] = mp;
    }
    __syncthreads();
    if (tid < 256) mip[(r * NCHUNK + chunk) * UU + tid] = Bf[tid] + Bf[256 + tid];
    __syncthreads();

    // ---- t1 = silu(m @ Wx1 /16): A -> B ; t2 = silu(t1 @ Wx2 /16): B -> A
    gemm64<8>(Ab, AS, wx1p, Bb, BS, 0.0625f, wave, col, q);
    __syncthreads();
    gemm64<8>(Bb, BS, wx2p, Ab, AS, 0.0625f, wave, col, q);
    __syncthreads();

    // ---- phi_x = t2 @ Wxl + bxl : A -> Bf (f32, 64x32); 1 tile/wave ----
    {
        int mt = wave >> 1, nt = wave & 1;
        f32x4 acc = {0.f, 0.f, 0.f, 0.f};
        const __bf16* xr = Ab + (mt * 16 + col) * AS + q * 8;
#pragma unroll
        for (int kt = 0; kt < 8; ++kt) {
            bf16v8 a = *(const bf16v8*)(xr + kt * 32);
            bf16v8 b = *(const bf16v8*)(wxlp + (kt * 32 + nt * 16 + col) * 32 + q * 8);
            acc = __builtin_amdgcn_mfma_f32_16x16x32_bf16(a, b, acc, 0, 0, 0);
        }
        float bias = bxl[nt * 16 + col];
#pragma unroll
        for (int i = 0; i < 4; ++i)
            Bf[(mt * 16 + q * 4 + i) * 32 + nt * 16 + col] = acc[i] + bias;
    }
    __syncthreads();

    // ---- shift partials: tid<384 -> (g16, sv, sc), 16 edges each ----
    if (tid < 384) {
        int g16 = tid / 96, rem = tid % 96;
        int sv = rem / 3, sc = rem - sv * 3;
        float r0 = nv[(r * 32 + sv) * 3 + 0];
        float r1 = nv[(r * 32 + sv) * 3 + 1];
        float r2 = nv[(r * 32 + sv) * 3 + 2];
        float sp = 0.f;
        for (int i = g16 * 16; i < g16 * 16 + 16; ++i) {
            int s = r + 1 + e0 + i; if (s >= NN) s -= NN;
            const float* ps = nv + (s * 32 + sv) * 3;
            float d0 = r0 - ps[0], d1 = r1 - ps[1], d2 = r2 - ps[2];
            float len = sqrtf(fmaxf(d0 * d0 + d1 * d1 + d2 * d2, 1e-20f));
            float d = (sc == 0) ? d0 : ((sc == 1) ? d1 : d2);
            sp += Bf[i * 32 + sv] * d / (1.f + len);
        }
        Af[tid] = sp;
    }
    __syncthreads();
    if (tid < 96)
        shiftp[(r * NCHUNK + chunk) * 96 + tid] =
            Af[tid] + Af[96 + tid] + Af[192 + tid] + Af[288 + tid];
}

// --------------------------- node-level epilogue ---------------------------
__global__ __launch_bounds__(256, 2)
void node_kernel(const float* __restrict__ nv, const float* __restrict__ nf,
                 const float* __restrict__ Wh1, const float* __restrict__ Wh2,
                 const float* __restrict__ Whl,
                 const float* __restrict__ shiftp, const float* __restrict__ mip,
                 float* __restrict__ out) {
    __shared__ float xs[384];
    __shared__ float h1[256];
    __shared__ float h2[256];
    const int n = blockIdx.x, tid = threadIdx.x;

    {   // sum 6 chunk partials of m_i
        float a = 0.f;
        for (int c = 0; c < NCHUNK; ++c) a += mip[(n * NCHUNK + c) * UU + tid];
        xs[tid] = a;
    }
    if (tid < 128) xs[256 + tid] = nf[n * HH + tid];
    if (tid < 96) {   // vectors_out = nv + shifts/(N-1)
        float s = 0.f;
        for (int c = 0; c < NCHUNK; ++c) s += shiftp[(n * NCHUNK + c) * 96 + tid];
        out[n * 96 + tid] = nv[n * 96 + tid] + s * (1.f / 383.f);
    }
    __syncthreads();

    float a0 = 0.f, a1 = 0.f, a2 = 0.f, a3 = 0.f;
    for (int k = 0; k < 384; k += 4) {
        a0 += xs[k]     * Wh1[k * 256 + tid];
        a1 += xs[k + 1] * Wh1[(k + 1) * 256 + tid];
        a2 += xs[k + 2] * Wh1[(k + 2) * 256 + tid];
        a3 += xs[k + 3] * Wh1[(k + 3) * 256 + tid];
    }
    float a = (a0 + a1 + a2 + a3) * 0.05103103630798288f;   // 1/sqrt(384)
    h1[tid] = a / (1.f + __expf(-a));
    __syncthreads();

    a0 = a1 = a2 = a3 = 0.f;
    for (int k = 0; k < 256; k += 4) {
        a0 += h1[k]     * Wh2[k * 256 + tid];
        a1 += h1[k + 1] * Wh2[(k + 1) * 256 + tid];
        a2 += h1[k + 2] * Wh2[(k + 2) * 256 + tid];
        a3 += h1[k + 3] * Wh2[(k + 3) * 256 + tid];
    }
    a = (a0 + a1 + a2 + a3) * 0.0625f;
    h2[tid] = a / (1.f + __expf(-a));
    __syncthreads();

    if (tid < 128) {
        a0 = a1 = a2 = a3 = 0.f;
        for (int k = 0; k < 256; k += 4) {
            a0 += h2[k]     * Whl[k * 128 + tid];
            a1 += h2[k + 1] * Whl[(k + 1) * 128 + tid];
            a2 += h2[k + 2] * Whl[(k + 2) * 128 + tid];
            a3 += h2[k + 3] * Whl[(k + 3) * 128 + tid];
        }
        out[NN * 96 + n * HH + tid] = (a0 + a1 + a2 + a3) * 0.0625f + nf[n * HH + tid];
    }
}

// ------------------------------- launcher ----------------------------------
extern "C" void kernel_launch(void* const* d_in, const int* in_sizes, int n_in,
                              void* d_out, int out_size, void* d_ws, size_t ws_size,
                              hipStream_t stream) {
    const float* nv   = (const float*)d_in[0];
    const float* nf   = (const float*)d_in[1];
    const float* We1  = (const float*)d_in[2];
    const float* We2  = (const float*)d_in[3];
    const float* Wx1  = (const float*)d_in[4];
    const float* Wx2  = (const float*)d_in[5];
    const float* Wxl  = (const float*)d_in[6];
    const float* bxl  = (const float*)d_in[7];
    const float* Winf = (const float*)d_in[8];
    const float* Wh1  = (const float*)d_in[9];
    const float* Wh2  = (const float*)d_in[10];
    const float* Whl  = (const float*)d_in[11];
    float* out = (float*)d_out;

    char* ws = (char*)d_ws;
    float*  mip    = (float*)ws;                        // 384*6*256*4 = 2359296 B
    float*  shiftp = (float*)(ws + 2359296);            // 384*6*96*4  =  884736 B
    __bf16* we1p   = (__bf16*)(ws + 3244032);           // 9*256*32*2  =  147456 B
    __bf16* we2p   = (__bf16*)(ws + 3391488);           // 8*256*32*2  =  131072 B
    __bf16* wx1p   = (__bf16*)(ws + 3522560);
    __bf16* wx2p   = (__bf16*)(ws + 3653632);
    __bf16* wxlp   = (__bf16*)(ws + 3784704);           // 8*32*32*2   =   16384 B

    repack_all<<<dim3(1088), 256, 0, stream>>>(We1, We2, Wx1, Wx2, Wxl,
                                               we1p, we2p, wx1p, wx2p, wxlp);

    edge_kernel<<<dim3(NCHUNK, NN), 512, 0, stream>>>(nv, nf, we1p, we2p, wx1p, wx2p,
                                                      wxlp, bxl, Winf, shiftp, mip);
    node_kernel<<<dim3(NN), 256, 0, stream>>>(nv, nf, Wh1, Wh2, Whl,
                                              shiftp, mip, out);
}

// Round 6
// 293.783 us; speedup vs baseline: 4.0542x; 1.0631x over previous
//
#include <hip/hip_runtime.h>
#include <hip/hip_bf16.h>

// EGCL (EGNN layer): N=384 nodes, V=32 vectors, H=128 feats, U=256 width.
// E = N*(N-1) = 147072 fully-connected edges. f32 in/out, bf16 MFMA compute.
// Edges grouped by RECEIVER r (s=(r+1+j')%N): segment sums are in-block
// reductions; [E,256] intermediates never touch HBM.
// R6: VALU diet. No fast-math in this TU => every f32 '/' was an IEEE
// div sequence (~10 instr) and sqrtf a guarded sequence; 128 divs/thread in
// silu epilogues alone. Replaced with v_rcp_f32 / v_sqrt_f32 intrinsics.
// Layer scales folded into repacked weights; phi_x bias folded into acc init.

#define NN 384
#define VV 32
#define HH 128
#define UU 256
#define MM 64            // edges per block
#define NCHUNK 6         // 6*64 = 384 = 383 edges + 1 pad
#define AS 296           // A-buffer row stride (288-wide ef, +8 pad)
#define BS 264           // B-buffer row stride (256-wide, +8 pad)

typedef __bf16 bf16v8 __attribute__((ext_vector_type(8)));
typedef __bf16 bf16v4 __attribute__((ext_vector_type(4)));
typedef float  f32x4  __attribute__((ext_vector_type(4)));

__device__ __forceinline__ float fast_rcp(float x) { return __builtin_amdgcn_rcpf(x); }
__device__ __forceinline__ float fast_sqrt(float x) { return __builtin_amdgcn_sqrtf(x); }
__device__ __forceinline__ float fast_silu(float v) {
    return v * __builtin_amdgcn_rcpf(1.f + __expf(-v));
}

// ---- fused weight repack: P[kt][n][kk] = (bf16)(scale * W[kt*32+kk][n]) ----
__global__ void repack_all(const float* __restrict__ We1, const float* __restrict__ We2,
                           const float* __restrict__ Wx1, const float* __restrict__ Wx2,
                           const float* __restrict__ Wxl,
                           __bf16* __restrict__ we1p, __bf16* __restrict__ we2p,
                           __bf16* __restrict__ wx1p, __bf16* __restrict__ wx2p,
                           __bf16* __restrict__ wxlp) {
    int t = blockIdx.x * 256 + threadIdx.x;
    const float* src; __bf16* dst; int Nout; int idx; float scale;
    if (t < 73728)       { src = We1; dst = we1p; Nout = 256; idx = t;          scale = 0.05892556509887896f; }
    else if (t < 139264) { src = We2; dst = we2p; Nout = 256; idx = t - 73728;  scale = 0.0625f; }
    else if (t < 204800) { src = Wx1; dst = wx1p; Nout = 256; idx = t - 139264; scale = 0.0625f; }
    else if (t < 270336) { src = Wx2; dst = wx2p; Nout = 256; idx = t - 204800; scale = 0.0625f; }
    else if (t < 278528) { src = Wxl; dst = wxlp; Nout = 32;  idx = t - 270336; scale = 1.0f; }
    else return;
    int kt  = idx / (Nout * 32);
    int rem = idx - kt * Nout * 32;
    int n   = rem >> 5;
    int kk  = rem & 31;
    dst[idx] = (__bf16)(src[(kt * 32 + kk) * Nout + n] * scale);
}

// ---- one 64x256 GEMM layer: Y = silu(X @ Wp), 8 waves cooperate ----------
// wave = (mh 0..1)*4 + (cq 0..3): rows mh*32+mt*16 (mt<2), cols cq*64+nt*16
template <int KT>
__device__ __forceinline__ void gemm64(const __bf16* X, int xs,
                                       const __bf16* __restrict__ P,
                                       __bf16* Y, int ys,
                                       int wave, int col, int q) {
    const int mh = wave >> 2, cq = wave & 3;
    f32x4 acc[2][4] = {};
    const __bf16* xr = X + (mh * 32 + col) * xs + q * 8;
    const __bf16* pb = P + (cq * 64 + col) * 32 + q * 8;
#pragma unroll
    for (int kt = 0; kt < KT; ++kt) {
        bf16v8 a[2], b[4];
#pragma unroll
        for (int mt = 0; mt < 2; ++mt)
            a[mt] = *(const bf16v8*)(xr + mt * 16 * xs + kt * 32);
#pragma unroll
        for (int nt = 0; nt < 4; ++nt)
            b[nt] = *(const bf16v8*)(pb + kt * (UU * 32) + nt * (16 * 32));
#pragma unroll
        for (int mt = 0; mt < 2; ++mt)
#pragma unroll
            for (int nt = 0; nt < 4; ++nt)
                acc[mt][nt] = __builtin_amdgcn_mfma_f32_16x16x32_bf16(a[mt], b[nt], acc[mt][nt], 0, 0, 0);
    }
#pragma unroll
    for (int mt = 0; mt < 2; ++mt)
#pragma unroll
        for (int nt = 0; nt < 4; ++nt)
#pragma unroll
            for (int i = 0; i < 4; ++i)
                Y[(mh * 32 + mt * 16 + q * 4 + i) * ys + cq * 64 + nt * 16 + col] =
                    (__bf16)fast_silu(acc[mt][nt][i]);
}

// --------------------------- fused edge kernel -----------------------------
__global__ __launch_bounds__(512, 4)
void edge_kernel(const float* __restrict__ nv, const float* __restrict__ nf,
                 const __bf16* __restrict__ we1p, const __bf16* __restrict__ we2p,
                 const __bf16* __restrict__ wx1p, const __bf16* __restrict__ wx2p,
                 const __bf16* __restrict__ wxlp, const float* __restrict__ bxl,
                 const float* __restrict__ winf,
                 float* __restrict__ shiftp, float* __restrict__ mip) {
    __shared__ __align__(16) __bf16 Ab[MM * AS];   // ef -> m -> t2 -> spart
    __shared__ __align__(16) __bf16 Bb[MM * BS];   // h1 -> scratch -> t1 -> phix(f32)
    __shared__ float gateb[MM];

    float* Bf = (float*)Bb;    // scratch / phix views
    float* Af = (float*)Ab;    // shift-partial view

    const int tid  = threadIdx.x;
    const int wave = tid >> 6;
    const int lane = tid & 63;
    const int col  = lane & 15;
    const int q    = lane >> 4;
    const int r     = blockIdx.y;
    const int chunk = blockIdx.x;
    const int e0    = chunk * MM;      // edge base within r's 383(+1 pad)

    // ---- stage edge features: [len2 | nf[s] | nf[r]] into A ----
#pragma unroll
    for (int p = tid; p < MM * 32; p += 512) {
        int i = p >> 5, v = p & 31;
        int s = r + 1 + e0 + i; if (s >= NN) s -= NN;
        const float* pr = nv + (r * 32 + v) * 3;
        const float* ps = nv + (s * 32 + v) * 3;
        float d0 = pr[0] - ps[0];
        float d1 = pr[1] - ps[1];
        float d2 = pr[2] - ps[2];
        Ab[i * AS + v] = (__bf16)(d0 * d0 + d1 * d1 + d2 * d2);
    }
#pragma unroll
    for (int p = tid; p < MM * 32; p += 512) {
        int i = p >> 5, hc = (p & 31) << 2;
        int s = r + 1 + e0 + i; if (s >= NN) s -= NN;
        float4 fs = *(const float4*)(nf + s * HH + hc);
        float4 fr = *(const float4*)(nf + r * HH + hc);
        bf16v4 bs = { (__bf16)fs.x, (__bf16)fs.y, (__bf16)fs.z, (__bf16)fs.w };
        bf16v4 br = { (__bf16)fr.x, (__bf16)fr.y, (__bf16)fr.z, (__bf16)fr.w };
        *(bf16v4*)&Ab[i * AS + 32 + hc]  = bs;
        *(bf16v4*)&Ab[i * AS + 160 + hc] = br;
    }
    __syncthreads();

    // ---- h1 = silu(ef @ We1') : A -> B ----
    gemm64<9>(Ab, AS, we1p, Bb, BS, wave, col, q);
    __syncthreads();
    // ---- m = silu(h1 @ We2') : B -> A ----
    gemm64<8>(Bb, BS, we2p, Ab, AS, wave, col, q);
    __syncthreads();

    // ---- gate e = sigmoid(m @ Winf / 16); partials in B scratch ----
    {
        int i = tid >> 3, kq = (tid & 7) * 32;
        const __bf16* mrow = Ab + i * AS + kq;
        const float*  wrow = winf + kq;
        float g = 0.f;
#pragma unroll
        for (int k = 0; k < 32; ++k)
            g += (float)mrow[k] * wrow[k];
        Bf[tid] = g;
    }
    __syncthreads();
    if (tid < MM) {
        float g = 0.f;
#pragma unroll
        for (int p8 = 0; p8 < 8; ++p8) g += Bf[tid * 8 + p8];
        gateb[tid] = (e0 + tid == NN - 1) ? 0.f     // self-edge pad
                                          : fast_rcp(1.f + __expf(-g * 0.0625f));
    }
    __syncthreads();

    // ---- m_i partials: col=tid&255, half=tid>>8 (32 edges each) ----
    {
        int c = tid & 255, ih = (tid >> 8) * 32;
        const __bf16* mcol = Ab + ih * AS + c;
        const float*  gp   = gateb + ih;
        float mp = 0.f;
#pragma unroll
        for (int i = 0; i < 32; ++i)
            mp += (float)mcol[i * AS] * gp[i];
        Bf[tid] = mp;
    }
    __syncthreads();
    if (tid < 256) mip[(r * NCHUNK + chunk) * UU + tid] = Bf[tid] + Bf[256 + tid];
    __syncthreads();

    // ---- t1 = silu(m @ Wx1'): A -> B ; t2 = silu(t1 @ Wx2'): B -> A ----
    gemm64<8>(Ab, AS, wx1p, Bb, BS, wave, col, q);
    __syncthreads();
    gemm64<8>(Bb, BS, wx2p, Ab, AS, wave, col, q);
    __syncthreads();

    // ---- phi_x = t2 @ Wxl + bxl : A -> Bf (f32, 64x32); bias in acc init --
    {
        int mt = wave >> 1, nt = wave & 1;
        float bias = bxl[nt * 16 + col];
        f32x4 acc = {bias, bias, bias, bias};
        const __bf16* xr = Ab + (mt * 16 + col) * AS + q * 8;
#pragma unroll
        for (int kt = 0; kt < 8; ++kt) {
            bf16v8 a = *(const bf16v8*)(xr + kt * 32);
            bf16v8 b = *(const bf16v8*)(wxlp + (kt * 32 + nt * 16 + col) * 32 + q * 8);
            acc = __builtin_amdgcn_mfma_f32_16x16x32_bf16(a, b, acc, 0, 0, 0);
        }
#pragma unroll
        for (int i = 0; i < 4; ++i)
            Bf[(mt * 16 + q * 4 + i) * 32 + nt * 16 + col] = acc[i];
    }
    __syncthreads();

    // ---- shift partials: tid<384 -> (g16, sv, sc), 16 edges each ----
    if (tid < 384) {
        int g16 = tid / 96, rem = tid % 96;
        int sv = rem / 3, sc = rem - sv * 3;
        float r0 = nv[(r * 32 + sv) * 3 + 0];
        float r1 = nv[(r * 32 + sv) * 3 + 1];
        float r2 = nv[(r * 32 + sv) * 3 + 2];
        float sp = 0.f;
#pragma unroll
        for (int i = g16 * 16; i < g16 * 16 + 16; ++i) {
            int s = r + 1 + e0 + i; if (s >= NN) s -= NN;
            const float* ps = nv + (s * 32 + sv) * 3;
            float d0 = r0 - ps[0], d1 = r1 - ps[1], d2 = r2 - ps[2];
            float len = fast_sqrt(fmaxf(d0 * d0 + d1 * d1 + d2 * d2, 1e-20f));
            float d = (sc == 0) ? d0 : ((sc == 1) ? d1 : d2);
            sp += Bf[i * 32 + sv] * d * fast_rcp(1.f + len);
        }
        Af[tid] = sp;
    }
    __syncthreads();
    if (tid < 96)
        shiftp[(r * NCHUNK + chunk) * 96 + tid] =
            Af[tid] + Af[96 + tid] + Af[192 + tid] + Af[288 + tid];
}

// --------------------------- node-level epilogue ---------------------------
__global__ __launch_bounds__(256, 2)
void node_kernel(const float* __restrict__ nv, const float* __restrict__ nf,
                 const float* __restrict__ Wh1, const float* __restrict__ Wh2,
                 const float* __restrict__ Whl,
                 const float* __restrict__ shiftp, const float* __restrict__ mip,
                 float* __restrict__ out) {
    __shared__ float xs[384];
    __shared__ float h1[256];
    __shared__ float h2[256];
    const int n = blockIdx.x, tid = threadIdx.x;

    {   // sum 6 chunk partials of m_i
        float a = 0.f;
#pragma unroll
        for (int c = 0; c < NCHUNK; ++c) a += mip[(n * NCHUNK + c) * UU + tid];
        xs[tid] = a;
    }
    if (tid < 128) xs[256 + tid] = nf[n * HH + tid];
    if (tid < 96) {   // vectors_out = nv + shifts/(N-1)
        float s = 0.f;
#pragma unroll
        for (int c = 0; c < NCHUNK; ++c) s += shiftp[(n * NCHUNK + c) * 96 + tid];
        out[n * 96 + tid] = nv[n * 96 + tid] + s * (1.f / 383.f);
    }
    __syncthreads();

    float a0 = 0.f, a1 = 0.f, a2 = 0.f, a3 = 0.f;
    for (int k = 0; k < 384; k += 4) {
        a0 += xs[k]     * Wh1[k * 256 + tid];
        a1 += xs[k + 1] * Wh1[(k + 1) * 256 + tid];
        a2 += xs[k + 2] * Wh1[(k + 2) * 256 + tid];
        a3 += xs[k + 3] * Wh1[(k + 3) * 256 + tid];
    }
    float a = (a0 + a1 + a2 + a3) * 0.05103103630798288f;   // 1/sqrt(384)
    h1[tid] = fast_silu(a);
    __syncthreads();

    a0 = a1 = a2 = a3 = 0.f;
    for (int k = 0; k < 256; k += 4) {
        a0 += h1[k]     * Wh2[k * 256 + tid];
        a1 += h1[k + 1] * Wh2[(k + 1) * 256 + tid];
        a2 += h1[k + 2] * Wh2[(k + 2) * 256 + tid];
        a3 += h1[k + 3] * Wh2[(k + 3) * 256 + tid];
    }
    a = (a0 + a1 + a2 + a3) * 0.0625f;
    h2[tid] = fast_silu(a);
    __syncthreads();

    if (tid < 128) {
        a0 = a1 = a2 = a3 = 0.f;
        for (int k = 0; k < 256; k += 4) {
            a0 += h2[k]     * Whl[k * 128 + tid];
            a1 += h2[k + 1] * Whl[(k + 1) * 128 + tid];
            a2 += h2[k + 2] * Whl[(k + 2) * 128 + tid];
            a3 += h2[k + 3] * Whl[(k + 3) * 128 + tid];
        }
        out[NN * 96 + n * HH + tid] = (a0 + a1 + a2 + a3) * 0.0625f + nf[n * HH + tid];
    }
}

// ------------------------------- launcher ----------------------------------
extern "C" void kernel_launch(void* const* d_in, const int* in_sizes, int n_in,
                              void* d_out, int out_size, void* d_ws, size_t ws_size,
                              hipStream_t stream) {
    const float* nv   = (const float*)d_in[0];
    const float* nf   = (const float*)d_in[1];
    const float* We1  = (const float*)d_in[2];
    const float* We2  = (const float*)d_in[3];
    const float* Wx1  = (const float*)d_in[4];
    const float* Wx2  = (const float*)d_in[5];
    const float* Wxl  = (const float*)d_in[6];
    const float* bxl  = (const float*)d_in[7];
    const float* Winf = (const float*)d_in[8];
    const float* Wh1  = (const float*)d_in[9];
    const float* Wh2  = (const float*)d_in[10];
    const float* Whl  = (const float*)d_in[11];
    float* out = (float*)d_out;

    char* ws = (char*)d_ws;
    float*  mip    = (float*)ws;                        // 384*6*256*4 = 2359296 B
    float*  shiftp = (float*)(ws + 2359296);            // 384*6*96*4  =  884736 B
    __bf16* we1p   = (__bf16*)(ws + 3244032);           // 9*256*32*2  =  147456 B
    __bf16* we2p   = (__bf16*)(ws + 3391488);           // 8*256*32*2  =  131072 B
    __bf16* wx1p   = (__bf16*)(ws + 3522560);
    __bf16* wx2p   = (__bf16*)(ws + 3653632);
    __bf16* wxlp   = (__bf16*)(ws + 3784704);           // 8*32*32*2   =   16384 B

    repack_all<<<dim3(1088), 256, 0, stream>>>(We1, We2, Wx1, Wx2, Wxl,
                                               we1p, we2p, wx1p, wx2p, wxlp);

    edge_kernel<<<dim3(NCHUNK, NN), 512, 0, stream>>>(nv, nf, we1p, we2p, wx1p, wx2p,
                                                      wxlp, bxl, Winf, shiftp, mip);
    node_kernel<<<dim3(NN), 256, 0, stream>>>(nv, nf, Wh1, Wh2, Whl,
                                              shiftp, mip, out);
}

// Round 7
// 230.161 us; speedup vs baseline: 5.1749x; 1.2764x over previous
//
#include <hip/hip_runtime.h>
#include <hip/hip_bf16.h>

// EGCL (EGNN layer): N=384 nodes, V=32 vectors, H=128 feats, U=256 width.
// E = N*(N-1) = 147072 fully-connected edges. f32 in/out, bf16 MFMA compute.
// Edges grouped by RECEIVER r (s=(r+1+j')%N): segment sums are in-block
// reductions; [E,256] intermediates never touch HBM.
// R7: (1) wave tile 64x32 (was 32x64) -> no duplicate B-panel reads per
// block, halves L2 weight traffic; (2) explicit 1-deep B prefetch in K-loop
// to hide ~200cyc L2 latency (R6 had VGPR=64, ~2 loads in flight);
// (3) nf[r]@We1[160:288] is block-constant -> one matvec, folded into
// gemm1 acc init; gemm1 K 288->160, staging halved.

#define NN 384
#define VV 32
#define HH 128
#define UU 256
#define MM 64            // edges per block
#define NCHUNK 6         // 6*64 = 384 = 383 edges + 1 pad
#define SS 264           // LDS row stride for both buffers (256-wide, +8 pad)

typedef __bf16 bf16v8 __attribute__((ext_vector_type(8)));
typedef __bf16 bf16v4 __attribute__((ext_vector_type(4)));
typedef float  f32x4  __attribute__((ext_vector_type(4)));

__device__ __forceinline__ float fast_rcp(float x) { return __builtin_amdgcn_rcpf(x); }
__device__ __forceinline__ float fast_sqrt(float x) { return __builtin_amdgcn_sqrtf(x); }
__device__ __forceinline__ float fast_silu(float v) {
    return v * __builtin_amdgcn_rcpf(1.f + __expf(-v));
}

// ---- fused weight repack: P[kt][n][kk] = (bf16)(scale * W[kt*32+kk][n]) ----
__global__ void repack_all(const float* __restrict__ We1, const float* __restrict__ We2,
                           const float* __restrict__ Wx1, const float* __restrict__ Wx2,
                           const float* __restrict__ Wxl,
                           __bf16* __restrict__ we1p, __bf16* __restrict__ we2p,
                           __bf16* __restrict__ wx1p, __bf16* __restrict__ wx2p,
                           __bf16* __restrict__ wxlp) {
    int t = blockIdx.x * 256 + threadIdx.x;
    const float* src; __bf16* dst; int Nout; int idx; float scale;
    if (t < 73728)       { src = We1; dst = we1p; Nout = 256; idx = t;          scale = 0.05892556509887896f; }
    else if (t < 139264) { src = We2; dst = we2p; Nout = 256; idx = t - 73728;  scale = 0.0625f; }
    else if (t < 204800) { src = Wx1; dst = wx1p; Nout = 256; idx = t - 139264; scale = 0.0625f; }
    else if (t < 270336) { src = Wx2; dst = wx2p; Nout = 256; idx = t - 204800; scale = 0.0625f; }
    else if (t < 278528) { src = Wxl; dst = wxlp; Nout = 32;  idx = t - 270336; scale = 1.0f; }
    else return;
    int kt  = idx / (Nout * 32);
    int rem = idx - kt * Nout * 32;
    int n   = rem >> 5;
    int kk  = rem & 31;
    dst[idx] = (__bf16)(src[(kt * 32 + kk) * Nout + n] * scale);
}

// ---- one 64x256 GEMM layer: Y = silu(X @ Wp [+ cinit]), 8 waves ----------
// wave w owns cols w*32 + nt*16 (nt<2); 4 m-tiles cover all 64 rows.
// 1-deep explicit B prefetch (B comes from global/L2).
template <int KT>
__device__ __forceinline__ void gemm64(const __bf16* X, const __bf16* __restrict__ P,
                                       __bf16* Y, int wave, int col, int q,
                                       const float* cinit) {
    f32x4 acc[4][2];
    float iv0 = cinit ? cinit[wave * 32 + col]      : 0.f;
    float iv1 = cinit ? cinit[wave * 32 + 16 + col] : 0.f;
#pragma unroll
    for (int mt = 0; mt < 4; ++mt) {
        acc[mt][0] = (f32x4){iv0, iv0, iv0, iv0};
        acc[mt][1] = (f32x4){iv1, iv1, iv1, iv1};
    }
    const __bf16* xr = X + col * SS + q * 8;
    const __bf16* pb = P + (wave * 32 + col) * 32 + q * 8;
    bf16v8 bc0 = *(const bf16v8*)(pb);
    bf16v8 bc1 = *(const bf16v8*)(pb + 16 * 32);
#pragma unroll
    for (int kt = 0; kt < KT; ++kt) {
        bf16v8 a[4];
#pragma unroll
        for (int mt = 0; mt < 4; ++mt)
            a[mt] = *(const bf16v8*)(xr + mt * 16 * SS + kt * 32);
        bf16v8 bn0, bn1;
        if (kt + 1 < KT) {
            bn0 = *(const bf16v8*)(pb + (kt + 1) * (UU * 32));
            bn1 = *(const bf16v8*)(pb + (kt + 1) * (UU * 32) + 16 * 32);
        }
#pragma unroll
        for (int mt = 0; mt < 4; ++mt) {
            acc[mt][0] = __builtin_amdgcn_mfma_f32_16x16x32_bf16(a[mt], bc0, acc[mt][0], 0, 0, 0);
            acc[mt][1] = __builtin_amdgcn_mfma_f32_16x16x32_bf16(a[mt], bc1, acc[mt][1], 0, 0, 0);
        }
        if (kt + 1 < KT) { bc0 = bn0; bc1 = bn1; }
    }
#pragma unroll
    for (int mt = 0; mt < 4; ++mt)
#pragma unroll
        for (int nt = 0; nt < 2; ++nt)
#pragma unroll
            for (int i = 0; i < 4; ++i)
                Y[(mt * 16 + q * 4 + i) * SS + wave * 32 + nt * 16 + col] =
                    (__bf16)fast_silu(acc[mt][nt][i]);
}

// --------------------------- fused edge kernel -----------------------------
__global__ __launch_bounds__(512, 4)
void edge_kernel(const float* __restrict__ nv, const float* __restrict__ nf,
                 const __bf16* __restrict__ we1p, const __bf16* __restrict__ we2p,
                 const __bf16* __restrict__ wx1p, const __bf16* __restrict__ wx2p,
                 const __bf16* __restrict__ wxlp, const float* __restrict__ bxl,
                 const float* __restrict__ winf,
                 float* __restrict__ shiftp, float* __restrict__ mip) {
    __shared__ __align__(16) __bf16 Ab[MM * SS];   // ef -> m -> t2 -> spart
    __shared__ __align__(16) __bf16 Bb[MM * SS];   // h1 -> scratch -> t1 -> phix(f32)
    __shared__ float gateb[MM];
    __shared__ float cvec[UU];     // nf[r] @ We1'[160:288]  (block-constant)
    __shared__ float nfr[HH];

    float* Bf = (float*)Bb;    // scratch / phix views
    float* Af = (float*)Ab;    // shift-partial view

    const int tid  = threadIdx.x;
    const int wave = tid >> 6;
    const int lane = tid & 63;
    const int col  = lane & 15;
    const int q    = lane >> 4;
    const int r     = blockIdx.y;
    const int chunk = blockIdx.x;
    const int e0    = chunk * MM;      // edge base within r's 383(+1 pad)

    // ---- stage: nfr, len2 (cols 0..31), nf[s] (cols 32..159) ----
    if (tid < HH) nfr[tid] = nf[r * HH + tid];
#pragma unroll
    for (int p = tid; p < MM * 32; p += 512) {
        int i = p >> 5, v = p & 31;
        int s = r + 1 + e0 + i; if (s >= NN) s -= NN;
        const float* pr = nv + (r * 32 + v) * 3;
        const float* ps = nv + (s * 32 + v) * 3;
        float d0 = pr[0] - ps[0];
        float d1 = pr[1] - ps[1];
        float d2 = pr[2] - ps[2];
        Ab[i * SS + v] = (__bf16)(d0 * d0 + d1 * d1 + d2 * d2);
    }
#pragma unroll
    for (int p = tid; p < MM * 32; p += 512) {
        int i = p >> 5, hc = (p & 31) << 2;
        int s = r + 1 + e0 + i; if (s >= NN) s -= NN;
        float4 fs = *(const float4*)(nf + s * HH + hc);
        bf16v4 bs = { (__bf16)fs.x, (__bf16)fs.y, (__bf16)fs.z, (__bf16)fs.w };
        *(bf16v4*)&Ab[i * SS + 32 + hc] = bs;
    }
    __syncthreads();

    // ---- cvec[n] = sum_k nfr[k] * We1'[160+k][n]  (kt = 5..8) ----
    if (tid < UU) {
        float c = 0.f;
#pragma unroll
        for (int kt = 5; kt < 9; ++kt) {
            const __bf16* wrow = we1p + kt * (UU * 32) + tid * 32;
#pragma unroll
            for (int kk = 0; kk < 32; ++kk)
                c += (float)wrow[kk] * nfr[(kt - 5) * 32 + kk];
        }
        cvec[tid] = c;
    }
    __syncthreads();

    // ---- h1 = silu(ef @ We1'[0:160] + cvec) : A -> B ----
    gemm64<5>(Ab, we1p, Bb, wave, col, q, cvec);
    __syncthreads();
    // ---- m = silu(h1 @ We2') : B -> A ----
    gemm64<8>(Bb, we2p, Ab, wave, col, q, nullptr);
    __syncthreads();

    // ---- gate e = sigmoid(m @ Winf / 16); partials in B scratch ----
    {
        int i = tid >> 3, kq = (tid & 7) * 32;
        const __bf16* mrow = Ab + i * SS + kq;
        const float*  wrow = winf + kq;
        float g = 0.f;
#pragma unroll
        for (int k = 0; k < 32; ++k)
            g += (float)mrow[k] * wrow[k];
        Bf[tid] = g;
    }
    __syncthreads();
    if (tid < MM) {
        float g = 0.f;
#pragma unroll
        for (int p8 = 0; p8 < 8; ++p8) g += Bf[tid * 8 + p8];
        gateb[tid] = (e0 + tid == NN - 1) ? 0.f     // self-edge pad
                                          : fast_rcp(1.f + __expf(-g * 0.0625f));
    }
    __syncthreads();

    // ---- m_i partials: col=tid&255, half=tid>>8 (32 edges each) ----
    {
        int c = tid & 255, ih = (tid >> 8) * 32;
        const __bf16* mcol = Ab + ih * SS + c;
        const float*  gp   = gateb + ih;
        float mp = 0.f;
#pragma unroll
        for (int i = 0; i < 32; ++i)
            mp += (float)mcol[i * SS] * gp[i];
        Bf[tid] = mp;
    }
    __syncthreads();
    if (tid < 256) mip[(r * NCHUNK + chunk) * UU + tid] = Bf[tid] + Bf[256 + tid];
    __syncthreads();

    // ---- t1 = silu(m @ Wx1'): A -> B ; t2 = silu(t1 @ Wx2'): B -> A ----
    gemm64<8>(Ab, wx1p, Bb, wave, col, q, nullptr);
    __syncthreads();
    gemm64<8>(Bb, wx2p, Ab, wave, col, q, nullptr);
    __syncthreads();

    // ---- phi_x = t2 @ Wxl + bxl : A -> Bf (f32, 64x32); bias in acc init --
    {
        int mt = wave >> 1, nt = wave & 1;
        float bias = bxl[nt * 16 + col];
        f32x4 acc = {bias, bias, bias, bias};
        const __bf16* xr = Ab + (mt * 16 + col) * SS + q * 8;
#pragma unroll
        for (int kt = 0; kt < 8; ++kt) {
            bf16v8 a = *(const bf16v8*)(xr + kt * 32);
            bf16v8 b = *(const bf16v8*)(wxlp + (kt * 32 + nt * 16 + col) * 32 + q * 8);
            acc = __builtin_amdgcn_mfma_f32_16x16x32_bf16(a, b, acc, 0, 0, 0);
        }
#pragma unroll
        for (int i = 0; i < 4; ++i)
            Bf[(mt * 16 + q * 4 + i) * 32 + nt * 16 + col] = acc[i];
    }
    __syncthreads();

    // ---- shift partials: tid<384 -> (g16, sv, sc), 16 edges each ----
    if (tid < 384) {
        int g16 = tid / 96, rem = tid % 96;
        int sv = rem / 3, sc = rem - sv * 3;
        float r0 = nv[(r * 32 + sv) * 3 + 0];
        float r1 = nv[(r * 32 + sv) * 3 + 1];
        float r2 = nv[(r * 32 + sv) * 3 + 2];
        float sp = 0.f;
#pragma unroll
        for (int i = g16 * 16; i < g16 * 16 + 16; ++i) {
            int s = r + 1 + e0 + i; if (s >= NN) s -= NN;
            const float* ps = nv + (s * 32 + sv) * 3;
            float d0 = r0 - ps[0], d1 = r1 - ps[1], d2 = r2 - ps[2];
            float len = fast_sqrt(fmaxf(d0 * d0 + d1 * d1 + d2 * d2, 1e-20f));
            float d = (sc == 0) ? d0 : ((sc == 1) ? d1 : d2);
            sp += Bf[i * 32 + sv] * d * fast_rcp(1.f + len);
        }
        Af[tid] = sp;
    }
    __syncthreads();
    if (tid < 96)
        shiftp[(r * NCHUNK + chunk) * 96 + tid] =
            Af[tid] + Af[96 + tid] + Af[192 + tid] + Af[288 + tid];
}

// --------------------------- node-level epilogue ---------------------------
__global__ __launch_bounds__(256, 2)
void node_kernel(const float* __restrict__ nv, const float* __restrict__ nf,
                 const float* __restrict__ Wh1, const float* __restrict__ Wh2,
                 const float* __restrict__ Whl,
                 const float* __restrict__ shiftp, const float* __restrict__ mip,
                 float* __restrict__ out) {
    __shared__ float xs[384];
    __shared__ float h1[256];
    __shared__ float h2[256];
    const int n = blockIdx.x, tid = threadIdx.x;

    {   // sum 6 chunk partials of m_i
        float a = 0.f;
#pragma unroll
        for (int c = 0; c < NCHUNK; ++c) a += mip[(n * NCHUNK + c) * UU + tid];
        xs[tid] = a;
    }
    if (tid < 128) xs[256 + tid] = nf[n * HH + tid];
    if (tid < 96) {   // vectors_out = nv + shifts/(N-1)
        float s = 0.f;
#pragma unroll
        for (int c = 0; c < NCHUNK; ++c) s += shiftp[(n * NCHUNK + c) * 96 + tid];
        out[n * 96 + tid] = nv[n * 96 + tid] + s * (1.f / 383.f);
    }
    __syncthreads();

    float a0 = 0.f, a1 = 0.f, a2 = 0.f, a3 = 0.f;
    for (int k = 0; k < 384; k += 4) {
        a0 += xs[k]     * Wh1[k * 256 + tid];
        a1 += xs[k + 1] * Wh1[(k + 1) * 256 + tid];
        a2 += xs[k + 2] * Wh1[(k + 2) * 256 + tid];
        a3 += xs[k + 3] * Wh1[(k + 3) * 256 + tid];
    }
    float a = (a0 + a1 + a2 + a3) * 0.05103103630798288f;   // 1/sqrt(384)
    h1[tid] = fast_silu(a);
    __syncthreads();

    a0 = a1 = a2 = a3 = 0.f;
    for (int k = 0; k < 256; k += 4) {
        a0 += h1[k]     * Wh2[k * 256 + tid];
        a1 += h1[k + 1] * Wh2[(k + 1) * 256 + tid];
        a2 += h1[k + 2] * Wh2[(k + 2) * 256 + tid];
        a3 += h1[k + 3] * Wh2[(k + 3) * 256 + tid];
    }
    a = (a0 + a1 + a2 + a3) * 0.0625f;
    h2[tid] = fast_silu(a);
    __syncthreads();

    if (tid < 128) {
        a0 = a1 = a2 = a3 = 0.f;
        for (int k = 0; k < 256; k += 4) {
            a0 += h2[k]     * Whl[k * 128 + tid];
            a1 += h2[k + 1] * Whl[(k + 1) * 128 + tid];
            a2 += h2[k + 2] * Whl[(k + 2) * 128 + tid];
            a3 += h2[k + 3] * Whl[(k + 3) * 128 + tid];
        }
        out[NN * 96 + n * HH + tid] = (a0 + a1 + a2 + a3) * 0.0625f + nf[n * HH + tid];
    }
}

// ------------------------------- launcher ----------------------------------
extern "C" void kernel_launch(void* const* d_in, const int* in_sizes, int n_in,
                              void* d_out, int out_size, void* d_ws, size_t ws_size,
                              hipStream_t stream) {
    const float* nv   = (const float*)d_in[0];
    const float* nf   = (const float*)d_in[1];
    const float* We1  = (const float*)d_in[2];
    const float* We2  = (const float*)d_in[3];
    const float* Wx1  = (const float*)d_in[4];
    const float* Wx2  = (const float*)d_in[5];
    const float* Wxl  = (const float*)d_in[6];
    const float* bxl  = (const float*)d_in[7];
    const float* Winf = (const float*)d_in[8];
    const float* Wh1  = (const float*)d_in[9];
    const float* Wh2  = (const float*)d_in[10];
    const float* Whl  = (const float*)d_in[11];
    float* out = (float*)d_out;

    char* ws = (char*)d_ws;
    float*  mip    = (float*)ws;                        // 384*6*256*4 = 2359296 B
    float*  shiftp = (float*)(ws + 2359296);            // 384*6*96*4  =  884736 B
    __bf16* we1p   = (__bf16*)(ws + 3244032);           // 9*256*32*2  =  147456 B
    __bf16* we2p   = (__bf16*)(ws + 3391488);           // 8*256*32*2  =  131072 B
    __bf16* wx1p   = (__bf16*)(ws + 3522560);
    __bf16* wx2p   = (__bf16*)(ws + 3653632);
    __bf16* wxlp   = (__bf16*)(ws + 3784704);           // 8*32*32*2   =   16384 B

    repack_all<<<dim3(1088), 256, 0, stream>>>(We1, We2, Wx1, Wx2, Wxl,
                                               we1p, we2p, wx1p, wx2p, wxlp);

    edge_kernel<<<dim3(NCHUNK, NN), 512, 0, stream>>>(nv, nf, we1p, we2p, wx1p, wx2p,
                                                      wxlp, bxl, Winf, shiftp, mip);
    node_kernel<<<dim3(NN), 256, 0, stream>>>(nv, nf, Wh1, Wh2, Whl,
                                              shiftp, mip, out);
}

// Round 8
// 224.346 us; speedup vs baseline: 5.3090x; 1.0259x over previous
//
#include <hip/hip_runtime.h>
#include <hip/hip_bf16.h>

// EGCL (EGNN layer): N=384 nodes, V=32 vectors, H=128 feats, U=256 width.
// E = N*(N-1) = 147072 fully-connected edges. f32 in/out, bf16 MFMA compute.
// Edges grouped by RECEIVER r (s=(r+1+j')%N): segment sums are in-block
// reductions; [E,256] intermediates never touch HBM.
// R8: (1) all 256-wide GEMMs (edge AND node) use v_mfma_f32_32x32x16_bf16
// (half the MFMA instrs of 16x16x32, conflict-free epilogue writes);
// (2) node path MFMA-ized (R7 had a ~73us scalar-matvec tail);
// (3) weights repacked in two fragment formats (32-fmt for N=256 gemms,
// 16-fmt for Wxl N=32 / Whl N=128), scales folded.

#define NN 384
#define VV 32
#define HH 128
#define UU 256
#define MM 64            // edges per block
#define NCHUNK 6         // 6*64 = 384 = 383 edges + 1 pad
#define SS 264           // LDS row stride edge buffers (256-wide, +8 pad)
#define XS 392           // LDS row stride node xs buffer (384-wide, +8 pad)

typedef __bf16 bf16v8 __attribute__((ext_vector_type(8)));
typedef __bf16 bf16v4 __attribute__((ext_vector_type(4)));
typedef float  f32x4  __attribute__((ext_vector_type(4)));
typedef float  f32x16 __attribute__((ext_vector_type(16)));

__device__ __forceinline__ float fast_rcp(float x) { return __builtin_amdgcn_rcpf(x); }
__device__ __forceinline__ float fast_sqrt(float x) { return __builtin_amdgcn_sqrtf(x); }
__device__ __forceinline__ float fast_silu(float v) {
    return v * __builtin_amdgcn_rcpf(1.f + __expf(-v));
}

// ---------------- weight repack, two formats, scales folded ----------------
// 32-fmt (for 32x32x16 MFMA, N=256): P[kt][n][kk] = W[kt*16+kk][n], kk<16
// 16-fmt (for 16x16x32 MFMA):        P[kt][n][kk] = W[kt*32+kk][n], kk<32
__global__ void repack_all(const float* __restrict__ We1, const float* __restrict__ We2,
                           const float* __restrict__ Wx1, const float* __restrict__ Wx2,
                           const float* __restrict__ Wh1, const float* __restrict__ Wh2,
                           const float* __restrict__ Wxl, const float* __restrict__ Whl,
                           __bf16* __restrict__ we1p, __bf16* __restrict__ we2p,
                           __bf16* __restrict__ wx1p, __bf16* __restrict__ wx2p,
                           __bf16* __restrict__ wh1p, __bf16* __restrict__ wh2p,
                           __bf16* __restrict__ wxlp, __bf16* __restrict__ whlp) {
    const float s288 = 0.05892556509887896f;   // 1/sqrt(288)
    const float s384 = 0.05103103630798288f;   // 1/sqrt(384)
    const float s16  = 0.0625f;
    int t = blockIdx.x * 256 + threadIdx.x;
    const float* src; __bf16* dst; int Nout; int idx; float scale; int fmt16;
    if (t < 73728)       { src = We1; dst = we1p; Nout = 256; idx = t;          scale = s288; fmt16 = 0; }
    else if (t < 139264) { src = We2; dst = we2p; Nout = 256; idx = t - 73728;  scale = s16;  fmt16 = 0; }
    else if (t < 204800) { src = Wx1; dst = wx1p; Nout = 256; idx = t - 139264; scale = s16;  fmt16 = 0; }
    else if (t < 270336) { src = Wx2; dst = wx2p; Nout = 256; idx = t - 204800; scale = s16;  fmt16 = 0; }
    else if (t < 368640) { src = Wh1; dst = wh1p; Nout = 256; idx = t - 270336; scale = s384; fmt16 = 0; }
    else if (t < 434176) { src = Wh2; dst = wh2p; Nout = 256; idx = t - 368640; scale = s16;  fmt16 = 0; }
    else if (t < 442368) { src = Wxl; dst = wxlp; Nout = 32;  idx = t - 434176; scale = 1.0f; fmt16 = 1; }
    else if (t < 475136) { src = Whl; dst = whlp; Nout = 128; idx = t - 442368; scale = s16;  fmt16 = 1; }
    else return;
    int kw  = fmt16 ? 32 : 16;
    int kt  = idx / (Nout * kw);
    int rem = idx - kt * Nout * kw;
    int n   = rem / kw;
    int kk  = rem - n * kw;
    dst[idx] = (__bf16)(src[(kt * kw + kk) * Nout + n] * scale);
}

// ---- one 64x256 GEMM: Y = silu(X @ Wp [+ cinit]), 8 waves, 32x32x16 MFMA --
// wave w owns n-tile w (cols w*32..w*32+31); both 32-row m-tiles.
// A[m=lane&31][k=(lane>>5)*8+j]; B[k=(lane>>5)*8+j][n=lane&31];
// C col=lane&31, row=(reg&3)+8*(reg>>2)+4*(lane>>5).
template <int KT>
__device__ __forceinline__ void gemm32(const __bf16* X, int xs,
                                       const __bf16* __restrict__ P,
                                       __bf16* Y, int ys,
                                       int wave, int lane, const float* cinit) {
    const int m  = lane & 31;
    const int kh = lane >> 5;
    float iv = cinit ? cinit[wave * 32 + m] : 0.f;
    f32x16 acc0, acc1;
#pragma unroll
    for (int i = 0; i < 16; ++i) { acc0[i] = iv; acc1[i] = iv; }
    const __bf16* xr = X + m * xs + kh * 8;
    const __bf16* pb = P + (wave * 32 + m) * 16 + kh * 8;
    bf16v8 b0 = *(const bf16v8*)(pb);
    bf16v8 b1 = (KT > 1) ? *(const bf16v8*)(pb + 4096) : b0;
#pragma unroll
    for (int kt = 0; kt < KT; ++kt) {
        bf16v8 a0 = *(const bf16v8*)(xr + kt * 16);
        bf16v8 a1 = *(const bf16v8*)(xr + 32 * xs + kt * 16);
        bf16v8 bn = (kt + 2 < KT) ? *(const bf16v8*)(pb + (kt + 2) * 4096) : b0;
        acc0 = __builtin_amdgcn_mfma_f32_32x32x16_bf16(a0, b0, acc0, 0, 0, 0);
        acc1 = __builtin_amdgcn_mfma_f32_32x32x16_bf16(a1, b0, acc1, 0, 0, 0);
        b0 = b1; b1 = bn;
    }
#pragma unroll
    for (int reg = 0; reg < 16; ++reg) {
        int row = (reg & 3) + 8 * (reg >> 2) + 4 * kh;
        Y[row * ys + wave * 32 + m]        = (__bf16)fast_silu(acc0[reg]);
        Y[(32 + row) * ys + wave * 32 + m] = (__bf16)fast_silu(acc1[reg]);
    }
}

// --------------------------- fused edge kernel -----------------------------
__global__ __launch_bounds__(512, 4)
void edge_kernel(const float* __restrict__ nv, const float* __restrict__ nf,
                 const __bf16* __restrict__ we1p, const __bf16* __restrict__ we2p,
                 const __bf16* __restrict__ wx1p, const __bf16* __restrict__ wx2p,
                 const __bf16* __restrict__ wxlp, const float* __restrict__ bxl,
                 const float* __restrict__ winf,
                 float* __restrict__ shiftp, float* __restrict__ mip) {
    __shared__ __align__(16) __bf16 Ab[MM * SS];   // ef -> m -> t2 -> spart
    __shared__ __align__(16) __bf16 Bb[MM * SS];   // h1 -> scratch -> t1 -> phix(f32)
    __shared__ float gateb[MM];
    __shared__ float cvec[UU];     // nf[r] @ We1'[160:288]  (block-constant)
    __shared__ float nfr[HH];

    float* Bf = (float*)Bb;
    float* Af = (float*)Ab;

    const int tid  = threadIdx.x;
    const int wave = tid >> 6;
    const int lane = tid & 63;
    const int col  = lane & 15;
    const int q    = lane >> 4;
    const int r     = blockIdx.y;
    const int chunk = blockIdx.x;
    const int e0    = chunk * MM;

    // ---- stage: nfr, len2 (cols 0..31), nf[s] (cols 32..159) ----
    if (tid < HH) nfr[tid] = nf[r * HH + tid];
#pragma unroll
    for (int p = tid; p < MM * 32; p += 512) {
        int i = p >> 5, v = p & 31;
        int s = r + 1 + e0 + i; if (s >= NN) s -= NN;
        const float* pr = nv + (r * 32 + v) * 3;
        const float* ps = nv + (s * 32 + v) * 3;
        float d0 = pr[0] - ps[0];
        float d1 = pr[1] - ps[1];
        float d2 = pr[2] - ps[2];
        Ab[i * SS + v] = (__bf16)(d0 * d0 + d1 * d1 + d2 * d2);
    }
#pragma unroll
    for (int p = tid; p < MM * 32; p += 512) {
        int i = p >> 5, hc = (p & 31) << 2;
        int s = r + 1 + e0 + i; if (s >= NN) s -= NN;
        float4 fs = *(const float4*)(nf + s * HH + hc);
        bf16v4 bs = { (__bf16)fs.x, (__bf16)fs.y, (__bf16)fs.z, (__bf16)fs.w };
        *(bf16v4*)&Ab[i * SS + 32 + hc] = bs;
    }
    __syncthreads();

    // ---- cvec[n] = sum_k nfr[k] * We1'[160+k][n]  (kt16 = 10..17) ----
    if (tid < UU) {
        float c = 0.f;
#pragma unroll
        for (int kt = 10; kt < 18; ++kt) {
            const __bf16* wrow = we1p + kt * 4096 + tid * 16;
#pragma unroll
            for (int kk = 0; kk < 16; ++kk)
                c += (float)wrow[kk] * nfr[(kt - 10) * 16 + kk];
        }
        cvec[tid] = c;
    }
    __syncthreads();

    // ---- h1 = silu(ef @ We1'[0:160] + cvec) : A -> B ----
    gemm32<10>(Ab, SS, we1p, Bb, SS, wave, lane, cvec);
    __syncthreads();
    // ---- m = silu(h1 @ We2') : B -> A ----
    gemm32<16>(Bb, SS, we2p, Ab, SS, wave, lane, nullptr);
    __syncthreads();

    // ---- gate e = sigmoid(m @ Winf / 16); partials in B scratch ----
    {
        int i = tid >> 3, kq = (tid & 7) * 32;
        const __bf16* mrow = Ab + i * SS + kq;
        const float*  wrow = winf + kq;
        float g = 0.f;
#pragma unroll
        for (int k = 0; k < 32; ++k)
            g += (float)mrow[k] * wrow[k];
        Bf[tid] = g;
    }
    __syncthreads();
    if (tid < MM) {
        float g = 0.f;
#pragma unroll
        for (int p8 = 0; p8 < 8; ++p8) g += Bf[tid * 8 + p8];
        gateb[tid] = (e0 + tid == NN - 1) ? 0.f     // self-edge pad
                                          : fast_rcp(1.f + __expf(-g * 0.0625f));
    }
    __syncthreads();

    // ---- m_i partials: col=tid&255, half=tid>>8 (32 edges each) ----
    {
        int c = tid & 255, ih = (tid >> 8) * 32;
        const __bf16* mcol = Ab + ih * SS + c;
        const float*  gp   = gateb + ih;
        float mp = 0.f;
#pragma unroll
        for (int i = 0; i < 32; ++i)
            mp += (float)mcol[i * SS] * gp[i];
        Bf[tid] = mp;
    }
    __syncthreads();
    if (tid < 256) mip[(r * NCHUNK + chunk) * UU + tid] = Bf[tid] + Bf[256 + tid];
    __syncthreads();

    // ---- t1 = silu(m @ Wx1'): A -> B ; t2 = silu(t1 @ Wx2'): B -> A ----
    gemm32<16>(Ab, SS, wx1p, Bb, SS, wave, lane, nullptr);
    __syncthreads();
    gemm32<16>(Bb, SS, wx2p, Ab, SS, wave, lane, nullptr);
    __syncthreads();

    // ---- phi_x = t2 @ Wxl + bxl : A -> Bf (f32, 64x32); 16x16 MFMA ----
    {
        int mt = wave >> 1, nt = wave & 1;
        float bias = bxl[nt * 16 + col];
        f32x4 acc = {bias, bias, bias, bias};
        const __bf16* xr = Ab + (mt * 16 + col) * SS + q * 8;
#pragma unroll
        for (int kt = 0; kt < 8; ++kt) {
            bf16v8 a = *(const bf16v8*)(xr + kt * 32);
            bf16v8 b = *(const bf16v8*)(wxlp + kt * 1024 + (nt * 16 + col) * 32 + q * 8);
            acc = __builtin_amdgcn_mfma_f32_16x16x32_bf16(a, b, acc, 0, 0, 0);
        }
#pragma unroll
        for (int i = 0; i < 4; ++i)
            Bf[(mt * 16 + q * 4 + i) * 32 + nt * 16 + col] = acc[i];
    }
    __syncthreads();

    // ---- shift partials: tid<384 -> (g16, sv, sc), 16 edges each ----
    if (tid < 384) {
        int g16 = tid / 96, rem = tid % 96;
        int sv = rem / 3, sc = rem - sv * 3;
        float r0 = nv[(r * 32 + sv) * 3 + 0];
        float r1 = nv[(r * 32 + sv) * 3 + 1];
        float r2 = nv[(r * 32 + sv) * 3 + 2];
        float sp = 0.f;
#pragma unroll
        for (int i = g16 * 16; i < g16 * 16 + 16; ++i) {
            int s = r + 1 + e0 + i; if (s >= NN) s -= NN;
            const float* ps = nv + (s * 32 + sv) * 3;
            float d0 = r0 - ps[0], d1 = r1 - ps[1], d2 = r2 - ps[2];
            float len = fast_sqrt(fmaxf(d0 * d0 + d1 * d1 + d2 * d2, 1e-20f));
            float d = (sc == 0) ? d0 : ((sc == 1) ? d1 : d2);
            sp += Bf[i * 32 + sv] * d * fast_rcp(1.f + len);
        }
        Af[tid] = sp;
    }
    __syncthreads();
    if (tid < 96)
        shiftp[(r * NCHUNK + chunk) * 96 + tid] =
            Af[tid] + Af[96 + tid] + Af[192 + tid] + Af[288 + tid];
}

// ----------------- node-level epilogue (MFMA, 6 blocks) --------------------
__global__ __launch_bounds__(512)
void node_kernel(const float* __restrict__ nv, const float* __restrict__ nf,
                 const __bf16* __restrict__ wh1p, const __bf16* __restrict__ wh2p,
                 const __bf16* __restrict__ whlp,
                 const float* __restrict__ shiftp, const float* __restrict__ mip,
                 float* __restrict__ out) {
    __shared__ __align__(16) __bf16 xsb[MM * XS];   // [m_i | nf] 64x384
    __shared__ __align__(16) __bf16 h1b[MM * SS];
    __shared__ __align__(16) __bf16 h2b[MM * SS];
    const int tid  = threadIdx.x;
    const int wave = tid >> 6;
    const int lane = tid & 63;
    const int n0   = blockIdx.x * MM;

    // ---- stage xs = [sum_chunks m_i partials | nf] as bf16 ----
#pragma unroll
    for (int p = tid; p < MM * 256; p += 512) {
        int i = p >> 8, c = p & 255;
        float a = 0.f;
#pragma unroll
        for (int ch = 0; ch < NCHUNK; ++ch)
            a += mip[((n0 + i) * NCHUNK + ch) * UU + c];
        xsb[i * XS + c] = (__bf16)a;
    }
#pragma unroll
    for (int p = tid; p < MM * 128; p += 512) {
        int i = p >> 7, c = p & 127;
        xsb[i * XS + 256 + c] = (__bf16)nf[(n0 + i) * HH + c];
    }
    // ---- vectors_out = nv + sum_chunks shift / (N-1) ----
#pragma unroll
    for (int p = tid; p < MM * 96; p += 512) {
        int i = p / 96, j = p - i * 96;
        float s = 0.f;
#pragma unroll
        for (int ch = 0; ch < NCHUNK; ++ch)
            s += shiftp[((n0 + i) * NCHUNK + ch) * 96 + j];
        out[(n0 + i) * 96 + j] = nv[(n0 + i) * 96 + j] + s * (1.f / 383.f);
    }
    __syncthreads();

    // ---- h1 = silu(xs @ Wh1') ; h2 = silu(h1 @ Wh2') ----
    gemm32<24>(xsb, XS, wh1p, h1b, SS, wave, lane, nullptr);
    __syncthreads();
    gemm32<16>(h1b, SS, wh2p, h2b, SS, wave, lane, nullptr);
    __syncthreads();

    // ---- features_out = h2 @ Whl' + nf  (N=128, 16x16 MFMA, 8 n-tiles) ----
    {
        int col = lane & 15, q = lane >> 4;
        int n = wave * 16 + col;
#pragma unroll
        for (int mt = 0; mt < 4; ++mt) {
            f32x4 acc = {0.f, 0.f, 0.f, 0.f};
            const __bf16* xr = h2b + (mt * 16 + col) * SS + q * 8;
#pragma unroll
            for (int kt = 0; kt < 8; ++kt) {
                bf16v8 a = *(const bf16v8*)(xr + kt * 32);
                bf16v8 b = *(const bf16v8*)(whlp + kt * 4096 + n * 32 + q * 8);
                acc = __builtin_amdgcn_mfma_f32_16x16x32_bf16(a, b, acc, 0, 0, 0);
            }
#pragma unroll
            for (int i = 0; i < 4; ++i) {
                int row = mt * 16 + q * 4 + i;
                out[NN * 96 + (n0 + row) * HH + n] = acc[i] + nf[(n0 + row) * HH + n];
            }
        }
    }
}

// ------------------------------- launcher ----------------------------------
extern "C" void kernel_launch(void* const* d_in, const int* in_sizes, int n_in,
                              void* d_out, int out_size, void* d_ws, size_t ws_size,
                              hipStream_t stream) {
    const float* nv   = (const float*)d_in[0];
    const float* nf   = (const float*)d_in[1];
    const float* We1  = (const float*)d_in[2];
    const float* We2  = (const float*)d_in[3];
    const float* Wx1  = (const float*)d_in[4];
    const float* Wx2  = (const float*)d_in[5];
    const float* Wxl  = (const float*)d_in[6];
    const float* bxl  = (const float*)d_in[7];
    const float* Winf = (const float*)d_in[8];
    const float* Wh1  = (const float*)d_in[9];
    const float* Wh2  = (const float*)d_in[10];
    const float* Whl  = (const float*)d_in[11];
    float* out = (float*)d_out;

    char* ws = (char*)d_ws;
    float*  mip    = (float*)ws;                        // 384*6*256*4 = 2359296
    float*  shiftp = (float*)(ws + 2359296);            // 384*6*96*4  =  884736
    __bf16* we1p   = (__bf16*)(ws + 3244032);           // 73728*2  = 147456
    __bf16* we2p   = (__bf16*)(ws + 3391488);           // 65536*2  = 131072
    __bf16* wx1p   = (__bf16*)(ws + 3522560);           // 131072
    __bf16* wx2p   = (__bf16*)(ws + 3653632);           // 131072
    __bf16* wh1p   = (__bf16*)(ws + 3784704);           // 98304*2  = 196608
    __bf16* wh2p   = (__bf16*)(ws + 3981312);           // 131072
    __bf16* wxlp   = (__bf16*)(ws + 4112384);           // 8192*2   = 16384
    __bf16* whlp   = (__bf16*)(ws + 4128768);           // 32768*2  = 65536

    repack_all<<<dim3(1856), 256, 0, stream>>>(We1, We2, Wx1, Wx2, Wh1, Wh2, Wxl, Whl,
                                               we1p, we2p, wx1p, wx2p,
                                               wh1p, wh2p, wxlp, whlp);

    edge_kernel<<<dim3(NCHUNK, NN), 512, 0, stream>>>(nv, nf, we1p, we2p, wx1p, wx2p,
                                                      wxlp, bxl, Winf, shiftp, mip);
    node_kernel<<<dim3(NCHUNK), 512, 0, stream>>>(nv, nf, wh1p, wh2p, whlp,
                                                  shiftp, mip, out);
}

// Round 9
// 215.020 us; speedup vs baseline: 5.5393x; 1.0434x over previous
//
#include <hip/hip_runtime.h>
#include <hip/hip_bf16.h>

// EGCL (EGNN layer): N=384 nodes, V=32 vectors, H=128 feats, U=256 width.
// E = N*(N-1) = 147072 fully-connected edges. f32 in/out, bf16 MFMA compute.
// Edges grouped by RECEIVER r (s=(r+1+j')%N): segment sums are in-block
// reductions; [E,256] intermediates never touch HBM.
// R9: tail fix. R8's node path was 6 blocks on 256 CUs (~83us serial tail).
// Now: reduce_kernel (384 blocks) collapses chunk partials -> vectors_out +
// GEMM-ready xsg[384x384] bf16; node_kernel (12 blocks x 32 rows) runs the
// 3-layer node MLP with A read straight from L2-resident xsg.

#define NN 384
#define VV 32
#define HH 128
#define UU 256
#define MM 64            // edges per block
#define NCHUNK 6         // 6*64 = 384 = 383 edges + 1 pad
#define SS 264           // LDS row stride edge buffers (256-wide, +8 pad)

typedef __bf16 bf16v8 __attribute__((ext_vector_type(8)));
typedef __bf16 bf16v4 __attribute__((ext_vector_type(4)));
typedef float  f32x4  __attribute__((ext_vector_type(4)));
typedef float  f32x16 __attribute__((ext_vector_type(16)));

__device__ __forceinline__ float fast_rcp(float x) { return __builtin_amdgcn_rcpf(x); }
__device__ __forceinline__ float fast_sqrt(float x) { return __builtin_amdgcn_sqrtf(x); }
__device__ __forceinline__ float fast_silu(float v) {
    return v * __builtin_amdgcn_rcpf(1.f + __expf(-v));
}

// ---------------- weight repack, two formats, scales folded ----------------
// 32-fmt (for 32x32x16 MFMA, N=256): P[kt][n][kk] = W[kt*16+kk][n], kk<16
// 16-fmt (for 16x16x32 MFMA):        P[kt][n][kk] = W[kt*32+kk][n], kk<32
__global__ void repack_all(const float* __restrict__ We1, const float* __restrict__ We2,
                           const float* __restrict__ Wx1, const float* __restrict__ Wx2,
                           const float* __restrict__ Wh1, const float* __restrict__ Wh2,
                           const float* __restrict__ Wxl, const float* __restrict__ Whl,
                           __bf16* __restrict__ we1p, __bf16* __restrict__ we2p,
                           __bf16* __restrict__ wx1p, __bf16* __restrict__ wx2p,
                           __bf16* __restrict__ wh1p, __bf16* __restrict__ wh2p,
                           __bf16* __restrict__ wxlp, __bf16* __restrict__ whlp) {
    const float s288 = 0.05892556509887896f;   // 1/sqrt(288)
    const float s384 = 0.05103103630798288f;   // 1/sqrt(384)
    const float s16  = 0.0625f;
    int t = blockIdx.x * 256 + threadIdx.x;
    const float* src; __bf16* dst; int Nout; int idx; float scale; int fmt16;
    if (t < 73728)       { src = We1; dst = we1p; Nout = 256; idx = t;          scale = s288; fmt16 = 0; }
    else if (t < 139264) { src = We2; dst = we2p; Nout = 256; idx = t - 73728;  scale = s16;  fmt16 = 0; }
    else if (t < 204800) { src = Wx1; dst = wx1p; Nout = 256; idx = t - 139264; scale = s16;  fmt16 = 0; }
    else if (t < 270336) { src = Wx2; dst = wx2p; Nout = 256; idx = t - 204800; scale = s16;  fmt16 = 0; }
    else if (t < 368640) { src = Wh1; dst = wh1p; Nout = 256; idx = t - 270336; scale = s384; fmt16 = 0; }
    else if (t < 434176) { src = Wh2; dst = wh2p; Nout = 256; idx = t - 368640; scale = s16;  fmt16 = 0; }
    else if (t < 442368) { src = Wxl; dst = wxlp; Nout = 32;  idx = t - 434176; scale = 1.0f; fmt16 = 1; }
    else if (t < 475136) { src = Whl; dst = whlp; Nout = 128; idx = t - 442368; scale = s16;  fmt16 = 1; }
    else return;
    int kw  = fmt16 ? 32 : 16;
    int kt  = idx / (Nout * kw);
    int rem = idx - kt * Nout * kw;
    int n   = rem / kw;
    int kk  = rem - n * kw;
    dst[idx] = (__bf16)(src[(kt * kw + kk) * Nout + n] * scale);
}

// ---- 64x256 GEMM: Y = silu(X @ Wp [+ cinit]), 8 waves, 32x32x16 MFMA ------
// wave w owns n-tile w (cols w*32..w*32+31); both 32-row m-tiles.
template <int KT>
__device__ __forceinline__ void gemm32(const __bf16* X, int xs,
                                       const __bf16* __restrict__ P,
                                       __bf16* Y, int ys,
                                       int wave, int lane, const float* cinit) {
    const int m  = lane & 31;
    const int kh = lane >> 5;
    float iv = cinit ? cinit[wave * 32 + m] : 0.f;
    f32x16 acc0, acc1;
#pragma unroll
    for (int i = 0; i < 16; ++i) { acc0[i] = iv; acc1[i] = iv; }
    const __bf16* xr = X + m * xs + kh * 8;
    const __bf16* pb = P + (wave * 32 + m) * 16 + kh * 8;
    bf16v8 b0 = *(const bf16v8*)(pb);
    bf16v8 b1 = (KT > 1) ? *(const bf16v8*)(pb + 4096) : b0;
#pragma unroll
    for (int kt = 0; kt < KT; ++kt) {
        bf16v8 a0 = *(const bf16v8*)(xr + kt * 16);
        bf16v8 a1 = *(const bf16v8*)(xr + 32 * xs + kt * 16);
        bf16v8 bn = (kt + 2 < KT) ? *(const bf16v8*)(pb + (kt + 2) * 4096) : b0;
        acc0 = __builtin_amdgcn_mfma_f32_32x32x16_bf16(a0, b0, acc0, 0, 0, 0);
        acc1 = __builtin_amdgcn_mfma_f32_32x32x16_bf16(a1, b0, acc1, 0, 0, 0);
        b0 = b1; b1 = bn;
    }
#pragma unroll
    for (int reg = 0; reg < 16; ++reg) {
        int row = (reg & 3) + 8 * (reg >> 2) + 4 * kh;
        Y[row * ys + wave * 32 + m]        = (__bf16)fast_silu(acc0[reg]);
        Y[(32 + row) * ys + wave * 32 + m] = (__bf16)fast_silu(acc1[reg]);
    }
}

// ---- 32x256 GEMM (single m-tile): Y = silu(X @ Wp), 8 waves ---------------
template <int KT>
__device__ __forceinline__ void gemmS(const __bf16* X, int xs,
                                      const __bf16* __restrict__ P,
                                      __bf16* Y, int ys, int wave, int lane) {
    const int m  = lane & 31;
    const int kh = lane >> 5;
    f32x16 acc = {};
    const __bf16* xr = X + m * xs + kh * 8;
    const __bf16* pb = P + (wave * 32 + m) * 16 + kh * 8;
    bf16v8 b0 = *(const bf16v8*)(pb);
    bf16v8 b1 = (KT > 1) ? *(const bf16v8*)(pb + 4096) : b0;
#pragma unroll
    for (int kt = 0; kt < KT; ++kt) {
        bf16v8 a0 = *(const bf16v8*)(xr + kt * 16);
        bf16v8 bn = (kt + 2 < KT) ? *(const bf16v8*)(pb + (kt + 2) * 4096) : b0;
        acc = __builtin_amdgcn_mfma_f32_32x32x16_bf16(a0, b0, acc, 0, 0, 0);
        b0 = b1; b1 = bn;
    }
#pragma unroll
    for (int reg = 0; reg < 16; ++reg) {
        int row = (reg & 3) + 8 * (reg >> 2) + 4 * kh;
        Y[row * ys + wave * 32 + m] = (__bf16)fast_silu(acc[reg]);
    }
}

// --------------------------- fused edge kernel -----------------------------
__global__ __launch_bounds__(512, 4)
void edge_kernel(const float* __restrict__ nv, const float* __restrict__ nf,
                 const __bf16* __restrict__ we1p, const __bf16* __restrict__ we2p,
                 const __bf16* __restrict__ wx1p, const __bf16* __restrict__ wx2p,
                 const __bf16* __restrict__ wxlp, const float* __restrict__ bxl,
                 const float* __restrict__ winf,
                 float* __restrict__ shiftp, float* __restrict__ mip) {
    __shared__ __align__(16) __bf16 Ab[MM * SS];   // ef -> m -> t2 -> spart
    __shared__ __align__(16) __bf16 Bb[MM * SS];   // h1 -> scratch -> t1 -> phix(f32)
    __shared__ float gateb[MM];
    __shared__ float cvec[UU];     // nf[r] @ We1'[160:288]  (block-constant)
    __shared__ float nfr[HH];

    float* Bf = (float*)Bb;
    float* Af = (float*)Ab;

    const int tid  = threadIdx.x;
    const int wave = tid >> 6;
    const int lane = tid & 63;
    const int col  = lane & 15;
    const int q    = lane >> 4;
    const int r     = blockIdx.y;
    const int chunk = blockIdx.x;
    const int e0    = chunk * MM;

    // ---- stage: nfr, len2 (cols 0..31), nf[s] (cols 32..159) ----
    if (tid < HH) nfr[tid] = nf[r * HH + tid];
#pragma unroll
    for (int p = tid; p < MM * 32; p += 512) {
        int i = p >> 5, v = p & 31;
        int s = r + 1 + e0 + i; if (s >= NN) s -= NN;
        const float* pr = nv + (r * 32 + v) * 3;
        const float* ps = nv + (s * 32 + v) * 3;
        float d0 = pr[0] - ps[0];
        float d1 = pr[1] - ps[1];
        float d2 = pr[2] - ps[2];
        Ab[i * SS + v] = (__bf16)(d0 * d0 + d1 * d1 + d2 * d2);
    }
#pragma unroll
    for (int p = tid; p < MM * 32; p += 512) {
        int i = p >> 5, hc = (p & 31) << 2;
        int s = r + 1 + e0 + i; if (s >= NN) s -= NN;
        float4 fs = *(const float4*)(nf + s * HH + hc);
        bf16v4 bs = { (__bf16)fs.x, (__bf16)fs.y, (__bf16)fs.z, (__bf16)fs.w };
        *(bf16v4*)&Ab[i * SS + 32 + hc] = bs;
    }
    __syncthreads();

    // ---- cvec[n] = sum_k nfr[k] * We1'[160+k][n]  (kt16 = 10..17) ----
    if (tid < UU) {
        float c = 0.f;
#pragma unroll
        for (int kt = 10; kt < 18; ++kt) {
            const __bf16* wrow = we1p + kt * 4096 + tid * 16;
#pragma unroll
            for (int kk = 0; kk < 16; ++kk)
                c += (float)wrow[kk] * nfr[(kt - 10) * 16 + kk];
        }
        cvec[tid] = c;
    }
    __syncthreads();

    // ---- h1 = silu(ef @ We1'[0:160] + cvec) : A -> B ----
    gemm32<10>(Ab, SS, we1p, Bb, SS, wave, lane, cvec);
    __syncthreads();
    // ---- m = silu(h1 @ We2') : B -> A ----
    gemm32<16>(Bb, SS, we2p, Ab, SS, wave, lane, nullptr);
    __syncthreads();

    // ---- gate e = sigmoid(m @ Winf / 16); partials in B scratch ----
    {
        int i = tid >> 3, kq = (tid & 7) * 32;
        const __bf16* mrow = Ab + i * SS + kq;
        const float*  wrow = winf + kq;
        float g = 0.f;
#pragma unroll
        for (int k = 0; k < 32; ++k)
            g += (float)mrow[k] * wrow[k];
        Bf[tid] = g;
    }
    __syncthreads();
    if (tid < MM) {
        float g = 0.f;
#pragma unroll
        for (int p8 = 0; p8 < 8; ++p8) g += Bf[tid * 8 + p8];
        gateb[tid] = (e0 + tid == NN - 1) ? 0.f     // self-edge pad
                                          : fast_rcp(1.f + __expf(-g * 0.0625f));
    }
    __syncthreads();

    // ---- m_i partials: col=tid&255, half=tid>>8 (32 edges each) ----
    {
        int c = tid & 255, ih = (tid >> 8) * 32;
        const __bf16* mcol = Ab + ih * SS + c;
        const float*  gp   = gateb + ih;
        float mp = 0.f;
#pragma unroll
        for (int i = 0; i < 32; ++i)
            mp += (float)mcol[i * SS] * gp[i];
        Bf[tid] = mp;
    }
    __syncthreads();
    if (tid < 256) mip[(r * NCHUNK + chunk) * UU + tid] = Bf[tid] + Bf[256 + tid];
    __syncthreads();

    // ---- t1 = silu(m @ Wx1'): A -> B ; t2 = silu(t1 @ Wx2'): B -> A ----
    gemm32<16>(Ab, SS, wx1p, Bb, SS, wave, lane, nullptr);
    __syncthreads();
    gemm32<16>(Bb, SS, wx2p, Ab, SS, wave, lane, nullptr);
    __syncthreads();

    // ---- phi_x = t2 @ Wxl + bxl : A -> Bf (f32, 64x32); 16x16 MFMA ----
    {
        int mt = wave >> 1, nt = wave & 1;
        float bias = bxl[nt * 16 + col];
        f32x4 acc = {bias, bias, bias, bias};
        const __bf16* xr = Ab + (mt * 16 + col) * SS + q * 8;
#pragma unroll
        for (int kt = 0; kt < 8; ++kt) {
            bf16v8 a = *(const bf16v8*)(xr + kt * 32);
            bf16v8 b = *(const bf16v8*)(wxlp + kt * 1024 + (nt * 16 + col) * 32 + q * 8);
            acc = __builtin_amdgcn_mfma_f32_16x16x32_bf16(a, b, acc, 0, 0, 0);
        }
#pragma unroll
        for (int i = 0; i < 4; ++i)
            Bf[(mt * 16 + q * 4 + i) * 32 + nt * 16 + col] = acc[i];
    }
    __syncthreads();

    // ---- shift partials: tid<384 -> (g16, sv, sc), 16 edges each ----
    if (tid < 384) {
        int g16 = tid / 96, rem = tid % 96;
        int sv = rem / 3, sc = rem - sv * 3;
        float r0 = nv[(r * 32 + sv) * 3 + 0];
        float r1 = nv[(r * 32 + sv) * 3 + 1];
        float r2 = nv[(r * 32 + sv) * 3 + 2];
        float sp = 0.f;
#pragma unroll
        for (int i = g16 * 16; i < g16 * 16 + 16; ++i) {
            int s = r + 1 + e0 + i; if (s >= NN) s -= NN;
            const float* ps = nv + (s * 32 + sv) * 3;
            float d0 = r0 - ps[0], d1 = r1 - ps[1], d2 = r2 - ps[2];
            float len = fast_sqrt(fmaxf(d0 * d0 + d1 * d1 + d2 * d2, 1e-20f));
            float d = (sc == 0) ? d0 : ((sc == 1) ? d1 : d2);
            sp += Bf[i * 32 + sv] * d * fast_rcp(1.f + len);
        }
        Af[tid] = sp;
    }
    __syncthreads();
    if (tid < 96)
        shiftp[(r * NCHUNK + chunk) * 96 + tid] =
            Af[tid] + Af[96 + tid] + Af[192 + tid] + Af[288 + tid];
}

// ---- reduce: collapse chunk partials -> vectors_out + xsg[384x384] bf16 ---
__global__ __launch_bounds__(384)
void reduce_kernel(const float* __restrict__ nv, const float* __restrict__ nf,
                   const float* __restrict__ shiftp, const float* __restrict__ mip,
                   __bf16* __restrict__ xsg, float* __restrict__ out) {
    const int n = blockIdx.x, tid = threadIdx.x;
    if (tid < 256) {
        float a = 0.f;
#pragma unroll
        for (int ch = 0; ch < NCHUNK; ++ch)
            a += mip[(n * NCHUNK + ch) * UU + tid];
        xsg[n * 384 + tid] = (__bf16)a;
    } else {
        xsg[n * 384 + tid] = (__bf16)nf[n * HH + (tid - 256)];
    }
    if (tid < 96) {
        float s = 0.f;
#pragma unroll
        for (int ch = 0; ch < NCHUNK; ++ch)
            s += shiftp[(n * NCHUNK + ch) * 96 + tid];
        out[n * 96 + tid] = nv[n * 96 + tid] + s * (1.f / 383.f);
    }
}

// ----------------- node MLP (MFMA, 12 blocks x 32 rows) --------------------
__global__ __launch_bounds__(512)
void node_kernel(const float* __restrict__ nf,
                 const __bf16* __restrict__ wh1p, const __bf16* __restrict__ wh2p,
                 const __bf16* __restrict__ whlp, const __bf16* __restrict__ xsg,
                 float* __restrict__ out) {
    __shared__ __align__(16) __bf16 h1b[32 * SS];
    __shared__ __align__(16) __bf16 h2b[32 * SS];
    const int tid  = threadIdx.x;
    const int wave = tid >> 6;
    const int lane = tid & 63;
    const int n0   = blockIdx.x * 32;

    // ---- h1 = silu(xs @ Wh1')  (A straight from L2-resident xsg) ----
    gemmS<24>(xsg + n0 * 384, 384, wh1p, h1b, SS, wave, lane);
    __syncthreads();
    // ---- h2 = silu(h1 @ Wh2') ----
    gemmS<16>(h1b, SS, wh2p, h2b, SS, wave, lane);
    __syncthreads();

    // ---- features_out = h2 @ Whl' + nf  (N=128, 16x16 MFMA, 8 n-tiles) ----
    {
        int col = lane & 15, q = lane >> 4;
        int n = wave * 16 + col;
#pragma unroll
        for (int mt = 0; mt < 2; ++mt) {
            f32x4 acc = {0.f, 0.f, 0.f, 0.f};
            const __bf16* xr = h2b + (mt * 16 + col) * SS + q * 8;
#pragma unroll
            for (int kt = 0; kt < 8; ++kt) {
                bf16v8 a = *(const bf16v8*)(xr + kt * 32);
                bf16v8 b = *(const bf16v8*)(whlp + kt * 4096 + n * 32 + q * 8);
                acc = __builtin_amdgcn_mfma_f32_16x16x32_bf16(a, b, acc, 0, 0, 0);
            }
#pragma unroll
            for (int i = 0; i < 4; ++i) {
                int row = n0 + mt * 16 + q * 4 + i;
                out[NN * 96 + row * HH + n] = acc[i] + nf[row * HH + n];
            }
        }
    }
}

// ------------------------------- launcher ----------------------------------
extern "C" void kernel_launch(void* const* d_in, const int* in_sizes, int n_in,
                              void* d_out, int out_size, void* d_ws, size_t ws_size,
                              hipStream_t stream) {
    const float* nv   = (const float*)d_in[0];
    const float* nf   = (const float*)d_in[1];
    const float* We1  = (const float*)d_in[2];
    const float* We2  = (const float*)d_in[3];
    const float* Wx1  = (const float*)d_in[4];
    const float* Wx2  = (const float*)d_in[5];
    const float* Wxl  = (const float*)d_in[6];
    const float* bxl  = (const float*)d_in[7];
    const float* Winf = (const float*)d_in[8];
    const float* Wh1  = (const float*)d_in[9];
    const float* Wh2  = (const float*)d_in[10];
    const float* Whl  = (const float*)d_in[11];
    float* out = (float*)d_out;

    char* ws = (char*)d_ws;
    float*  mip    = (float*)ws;                        // 384*6*256*4 = 2359296
    float*  shiftp = (float*)(ws + 2359296);            // 384*6*96*4  =  884736
    __bf16* we1p   = (__bf16*)(ws + 3244032);           // 147456
    __bf16* we2p   = (__bf16*)(ws + 3391488);           // 131072
    __bf16* wx1p   = (__bf16*)(ws + 3522560);           // 131072
    __bf16* wx2p   = (__bf16*)(ws + 3653632);           // 131072
    __bf16* wh1p   = (__bf16*)(ws + 3784704);           // 196608
    __bf16* wh2p   = (__bf16*)(ws + 3981312);           // 131072
    __bf16* wxlp   = (__bf16*)(ws + 4112384);           // 16384
    __bf16* whlp   = (__bf16*)(ws + 4128768);           // 65536
    __bf16* xsg    = (__bf16*)(ws + 4194304);           // 384*384*2 = 294912

    repack_all<<<dim3(1856), 256, 0, stream>>>(We1, We2, Wx1, Wx2, Wh1, Wh2, Wxl, Whl,
                                               we1p, we2p, wx1p, wx2p,
                                               wh1p, wh2p, wxlp, whlp);

    edge_kernel<<<dim3(NCHUNK, NN), 512, 0, stream>>>(nv, nf, we1p, we2p, wx1p, wx2p,
                                                      wxlp, bxl, Winf, shiftp, mip);
    reduce_kernel<<<dim3(NN), 384, 0, stream>>>(nv, nf, shiftp, mip, xsg, out);
    node_kernel<<<dim3(12), 512, 0, stream>>>(nf, wh1p, wh2p, whlp, xsg, out);
}

// Round 10
// 212.777 us; speedup vs baseline: 5.5977x; 1.0105x over previous
//
#include <hip/hip_runtime.h>
#include <hip/hip_bf16.h>

// EGCL (EGNN layer): N=384 nodes, V=32 vectors, H=128 feats, U=256 width.
// E = N*(N-1) = 147072 fully-connected edges. f32 in/out, bf16 MFMA compute.
// Edges grouped by RECEIVER r (s=(r+1+j')%N): segment sums are in-block
// reductions; [E,256] intermediates never touch HBM.
// R10: (1) reduce_kernel merged into node_kernel (12 blocks reduce their own
// chunk partials in staging) -> 3 launches, no xsg roundtrip; (2) edge shift
// phase: 1/(1+len) folded into phix buffer once per (edge,v) instead of the
// 3x-redundant per-(edge,v,c) norm recompute.

#define NN 384
#define VV 32
#define HH 128
#define UU 256
#define MM 64            // edges per block
#define NCHUNK 6         // 6*64 = 384 = 383 edges + 1 pad
#define SS 264           // LDS row stride edge buffers (256-wide, +8 pad)
#define XS 392           // node xs row stride (384-wide, +8 pad)

typedef __bf16 bf16v8 __attribute__((ext_vector_type(8)));
typedef __bf16 bf16v4 __attribute__((ext_vector_type(4)));
typedef float  f32x4  __attribute__((ext_vector_type(4)));
typedef float  f32x16 __attribute__((ext_vector_type(16)));

__device__ __forceinline__ float fast_rcp(float x) { return __builtin_amdgcn_rcpf(x); }
__device__ __forceinline__ float fast_sqrt(float x) { return __builtin_amdgcn_sqrtf(x); }
__device__ __forceinline__ float fast_silu(float v) {
    return v * __builtin_amdgcn_rcpf(1.f + __expf(-v));
}

// ---------------- weight repack, two formats, scales folded ----------------
// 32-fmt (for 32x32x16 MFMA, N=256): P[kt][n][kk] = W[kt*16+kk][n], kk<16
// 16-fmt (for 16x16x32 MFMA):        P[kt][n][kk] = W[kt*32+kk][n], kk<32
__global__ void repack_all(const float* __restrict__ We1, const float* __restrict__ We2,
                           const float* __restrict__ Wx1, const float* __restrict__ Wx2,
                           const float* __restrict__ Wh1, const float* __restrict__ Wh2,
                           const float* __restrict__ Wxl, const float* __restrict__ Whl,
                           __bf16* __restrict__ we1p, __bf16* __restrict__ we2p,
                           __bf16* __restrict__ wx1p, __bf16* __restrict__ wx2p,
                           __bf16* __restrict__ wh1p, __bf16* __restrict__ wh2p,
                           __bf16* __restrict__ wxlp, __bf16* __restrict__ whlp) {
    const float s288 = 0.05892556509887896f;   // 1/sqrt(288)
    const float s384 = 0.05103103630798288f;   // 1/sqrt(384)
    const float s16  = 0.0625f;
    int t = blockIdx.x * 256 + threadIdx.x;
    const float* src; __bf16* dst; int Nout; int idx; float scale; int fmt16;
    if (t < 73728)       { src = We1; dst = we1p; Nout = 256; idx = t;          scale = s288; fmt16 = 0; }
    else if (t < 139264) { src = We2; dst = we2p; Nout = 256; idx = t - 73728;  scale = s16;  fmt16 = 0; }
    else if (t < 204800) { src = Wx1; dst = wx1p; Nout = 256; idx = t - 139264; scale = s16;  fmt16 = 0; }
    else if (t < 270336) { src = Wx2; dst = wx2p; Nout = 256; idx = t - 204800; scale = s16;  fmt16 = 0; }
    else if (t < 368640) { src = Wh1; dst = wh1p; Nout = 256; idx = t - 270336; scale = s384; fmt16 = 0; }
    else if (t < 434176) { src = Wh2; dst = wh2p; Nout = 256; idx = t - 368640; scale = s16;  fmt16 = 0; }
    else if (t < 442368) { src = Wxl; dst = wxlp; Nout = 32;  idx = t - 434176; scale = 1.0f; fmt16 = 1; }
    else if (t < 475136) { src = Whl; dst = whlp; Nout = 128; idx = t - 442368; scale = s16;  fmt16 = 1; }
    else return;
    int kw  = fmt16 ? 32 : 16;
    int kt  = idx / (Nout * kw);
    int rem = idx - kt * Nout * kw;
    int n   = rem / kw;
    int kk  = rem - n * kw;
    dst[idx] = (__bf16)(src[(kt * kw + kk) * Nout + n] * scale);
}

// ---- 64x256 GEMM: Y = silu(X @ Wp [+ cinit]), 8 waves, 32x32x16 MFMA ------
template <int KT>
__device__ __forceinline__ void gemm32(const __bf16* X, int xs,
                                       const __bf16* __restrict__ P,
                                       __bf16* Y, int ys,
                                       int wave, int lane, const float* cinit) {
    const int m  = lane & 31;
    const int kh = lane >> 5;
    float iv = cinit ? cinit[wave * 32 + m] : 0.f;
    f32x16 acc0, acc1;
#pragma unroll
    for (int i = 0; i < 16; ++i) { acc0[i] = iv; acc1[i] = iv; }
    const __bf16* xr = X + m * xs + kh * 8;
    const __bf16* pb = P + (wave * 32 + m) * 16 + kh * 8;
    bf16v8 b0 = *(const bf16v8*)(pb);
    bf16v8 b1 = (KT > 1) ? *(const bf16v8*)(pb + 4096) : b0;
#pragma unroll
    for (int kt = 0; kt < KT; ++kt) {
        bf16v8 a0 = *(const bf16v8*)(xr + kt * 16);
        bf16v8 a1 = *(const bf16v8*)(xr + 32 * xs + kt * 16);
        bf16v8 bn = (kt + 2 < KT) ? *(const bf16v8*)(pb + (kt + 2) * 4096) : b0;
        acc0 = __builtin_amdgcn_mfma_f32_32x32x16_bf16(a0, b0, acc0, 0, 0, 0);
        acc1 = __builtin_amdgcn_mfma_f32_32x32x16_bf16(a1, b0, acc1, 0, 0, 0);
        b0 = b1; b1 = bn;
    }
#pragma unroll
    for (int reg = 0; reg < 16; ++reg) {
        int row = (reg & 3) + 8 * (reg >> 2) + 4 * kh;
        Y[row * ys + wave * 32 + m]        = (__bf16)fast_silu(acc0[reg]);
        Y[(32 + row) * ys + wave * 32 + m] = (__bf16)fast_silu(acc1[reg]);
    }
}

// ---- 32x256 GEMM (single m-tile): Y = silu(X @ Wp), 8 waves ---------------
template <int KT>
__device__ __forceinline__ void gemmS(const __bf16* X, int xs,
                                      const __bf16* __restrict__ P,
                                      __bf16* Y, int ys, int wave, int lane) {
    const int m  = lane & 31;
    const int kh = lane >> 5;
    f32x16 acc = {};
    const __bf16* xr = X + m * xs + kh * 8;
    const __bf16* pb = P + (wave * 32 + m) * 16 + kh * 8;
    bf16v8 b0 = *(const bf16v8*)(pb);
    bf16v8 b1 = (KT > 1) ? *(const bf16v8*)(pb + 4096) : b0;
#pragma unroll
    for (int kt = 0; kt < KT; ++kt) {
        bf16v8 a0 = *(const bf16v8*)(xr + kt * 16);
        bf16v8 bn = (kt + 2 < KT) ? *(const bf16v8*)(pb + (kt + 2) * 4096) : b0;
        acc = __builtin_amdgcn_mfma_f32_32x32x16_bf16(a0, b0, acc, 0, 0, 0);
        b0 = b1; b1 = bn;
    }
#pragma unroll
    for (int reg = 0; reg < 16; ++reg) {
        int row = (reg & 3) + 8 * (reg >> 2) + 4 * kh;
        Y[row * ys + wave * 32 + m] = (__bf16)fast_silu(acc[reg]);
    }
}

// --------------------------- fused edge kernel -----------------------------
__global__ __launch_bounds__(512, 4)
void edge_kernel(const float* __restrict__ nv, const float* __restrict__ nf,
                 const __bf16* __restrict__ we1p, const __bf16* __restrict__ we2p,
                 const __bf16* __restrict__ wx1p, const __bf16* __restrict__ wx2p,
                 const __bf16* __restrict__ wxlp, const float* __restrict__ bxl,
                 const float* __restrict__ winf,
                 float* __restrict__ shiftp, float* __restrict__ mip) {
    __shared__ __align__(16) __bf16 Ab[MM * SS];   // ef -> m -> t2 -> spart
    __shared__ __align__(16) __bf16 Bb[MM * SS];   // h1 -> scratch -> t1 -> phix(f32)
    __shared__ float gateb[MM];
    __shared__ float cvec[UU];     // nf[r] @ We1'[160:288]  (block-constant)
    __shared__ float nfr[HH];

    float* Bf = (float*)Bb;
    float* Af = (float*)Ab;

    const int tid  = threadIdx.x;
    const int wave = tid >> 6;
    const int lane = tid & 63;
    const int col  = lane & 15;
    const int q    = lane >> 4;
    const int r     = blockIdx.y;
    const int chunk = blockIdx.x;
    const int e0    = chunk * MM;

    // ---- stage: nfr, len2 (cols 0..31), nf[s] (cols 32..159) ----
    if (tid < HH) nfr[tid] = nf[r * HH + tid];
#pragma unroll
    for (int p = tid; p < MM * 32; p += 512) {
        int i = p >> 5, v = p & 31;
        int s = r + 1 + e0 + i; if (s >= NN) s -= NN;
        const float* pr = nv + (r * 32 + v) * 3;
        const float* ps = nv + (s * 32 + v) * 3;
        float d0 = pr[0] - ps[0];
        float d1 = pr[1] - ps[1];
        float d2 = pr[2] - ps[2];
        Ab[i * SS + v] = (__bf16)(d0 * d0 + d1 * d1 + d2 * d2);
    }
#pragma unroll
    for (int p = tid; p < MM * 32; p += 512) {
        int i = p >> 5, hc = (p & 31) << 2;
        int s = r + 1 + e0 + i; if (s >= NN) s -= NN;
        float4 fs = *(const float4*)(nf + s * HH + hc);
        bf16v4 bs = { (__bf16)fs.x, (__bf16)fs.y, (__bf16)fs.z, (__bf16)fs.w };
        *(bf16v4*)&Ab[i * SS + 32 + hc] = bs;
    }
    __syncthreads();

    // ---- cvec[n] = sum_k nfr[k] * We1'[160+k][n]  (kt16 = 10..17) ----
    if (tid < UU) {
        float c = 0.f;
#pragma unroll
        for (int kt = 10; kt < 18; ++kt) {
            const __bf16* wrow = we1p + kt * 4096 + tid * 16;
#pragma unroll
            for (int kk = 0; kk < 16; ++kk)
                c += (float)wrow[kk] * nfr[(kt - 10) * 16 + kk];
        }
        cvec[tid] = c;
    }
    __syncthreads();

    // ---- h1 = silu(ef @ We1'[0:160] + cvec) : A -> B ----
    gemm32<10>(Ab, SS, we1p, Bb, SS, wave, lane, cvec);
    __syncthreads();
    // ---- m = silu(h1 @ We2') : B -> A ----
    gemm32<16>(Bb, SS, we2p, Ab, SS, wave, lane, nullptr);
    __syncthreads();

    // ---- gate e = sigmoid(m @ Winf / 16); partials in B scratch ----
    {
        int i = tid >> 3, kq = (tid & 7) * 32;
        const __bf16* mrow = Ab + i * SS + kq;
        const float*  wrow = winf + kq;
        float g = 0.f;
#pragma unroll
        for (int k = 0; k < 32; ++k)
            g += (float)mrow[k] * wrow[k];
        Bf[tid] = g;
    }
    __syncthreads();
    if (tid < MM) {
        float g = 0.f;
#pragma unroll
        for (int p8 = 0; p8 < 8; ++p8) g += Bf[tid * 8 + p8];
        gateb[tid] = (e0 + tid == NN - 1) ? 0.f     // self-edge pad
                                          : fast_rcp(1.f + __expf(-g * 0.0625f));
    }
    __syncthreads();

    // ---- m_i partials: col=tid&255, half=tid>>8 (32 edges each) ----
    {
        int c = tid & 255, ih = (tid >> 8) * 32;
        const __bf16* mcol = Ab + ih * SS + c;
        const float*  gp   = gateb + ih;
        float mp = 0.f;
#pragma unroll
        for (int i = 0; i < 32; ++i)
            mp += (float)mcol[i * SS] * gp[i];
        Bf[tid] = mp;
    }
    __syncthreads();
    if (tid < 256) mip[(r * NCHUNK + chunk) * UU + tid] = Bf[tid] + Bf[256 + tid];
    __syncthreads();

    // ---- t1 = silu(m @ Wx1'): A -> B ; t2 = silu(t1 @ Wx2'): B -> A ----
    gemm32<16>(Ab, SS, wx1p, Bb, SS, wave, lane, nullptr);
    __syncthreads();
    gemm32<16>(Bb, SS, wx2p, Ab, SS, wave, lane, nullptr);
    __syncthreads();

    // ---- phi_x = t2 @ Wxl + bxl : A -> Bf (f32, 64x32); 16x16 MFMA ----
    {
        int mt = wave >> 1, nt = wave & 1;
        float bias = bxl[nt * 16 + col];
        f32x4 acc = {bias, bias, bias, bias};
        const __bf16* xr = Ab + (mt * 16 + col) * SS + q * 8;
#pragma unroll
        for (int kt = 0; kt < 8; ++kt) {
            bf16v8 a = *(const bf16v8*)(xr + kt * 32);
            bf16v8 b = *(const bf16v8*)(wxlp + kt * 1024 + (nt * 16 + col) * 32 + q * 8);
            acc = __builtin_amdgcn_mfma_f32_16x16x32_bf16(a, b, acc, 0, 0, 0);
        }
#pragma unroll
        for (int i = 0; i < 4; ++i)
            Bf[(mt * 16 + q * 4 + i) * 32 + nt * 16 + col] = acc[i];
    }
    __syncthreads();

    // ---- fold 1/(1+len) into phix: one norm per (edge, v) ----
    {
        int v = tid & 31;
        float r0 = nv[(r * 32 + v) * 3 + 0];
        float r1 = nv[(r * 32 + v) * 3 + 1];
        float r2 = nv[(r * 32 + v) * 3 + 2];
#pragma unroll
        for (int p = tid; p < MM * 32; p += 512) {
            int i = p >> 5;
            int s = r + 1 + e0 + i; if (s >= NN) s -= NN;
            const float* ps = nv + (s * 32 + v) * 3;
            float d0 = r0 - ps[0], d1 = r1 - ps[1], d2 = r2 - ps[2];
            float len = fast_sqrt(fmaxf(d0 * d0 + d1 * d1 + d2 * d2, 1e-20f));
            Bf[p] *= fast_rcp(1.f + len);
        }
    }
    __syncthreads();

    // ---- shift partials: tid<384 -> (g16, sv, sc), 16 edges each ----
    if (tid < 384) {
        int g16 = tid / 96, rem = tid % 96;
        int sv = rem / 3, sc = rem - sv * 3;
        float rc = nv[(r * 32 + sv) * 3 + sc];
        float sp = 0.f;
#pragma unroll
        for (int i = g16 * 16; i < g16 * 16 + 16; ++i) {
            int s = r + 1 + e0 + i; if (s >= NN) s -= NN;
            float d = rc - nv[(s * 32 + sv) * 3 + sc];
            sp += Bf[i * 32 + sv] * d;
        }
        Af[tid] = sp;
    }
    __syncthreads();
    if (tid < 96)
        shiftp[(r * NCHUNK + chunk) * 96 + tid] =
            Af[tid] + Af[96 + tid] + Af[192 + tid] + Af[288 + tid];
}

// ------- node MLP + fused chunk reduction (12 blocks x 32 rows) ------------
__global__ __launch_bounds__(512)
void node_kernel(const float* __restrict__ nv, const float* __restrict__ nf,
                 const __bf16* __restrict__ wh1p, const __bf16* __restrict__ wh2p,
                 const __bf16* __restrict__ whlp,
                 const float* __restrict__ shiftp, const float* __restrict__ mip,
                 float* __restrict__ out) {
    __shared__ __align__(16) __bf16 xsb[32 * XS];   // [m_i | nf] 32x384
    __shared__ __align__(16) __bf16 h1b[32 * SS];
    __shared__ __align__(16) __bf16 h2b[32 * SS];
    const int tid  = threadIdx.x;
    const int wave = tid >> 6;
    const int lane = tid & 63;
    const int n0   = blockIdx.x * 32;

    // ---- reduce chunk partials of m_i into xs; stage nf; vectors_out ----
#pragma unroll
    for (int p = tid; p < 32 * 256; p += 512) {
        int i = p >> 8, c = p & 255;
        float a = 0.f;
#pragma unroll
        for (int ch = 0; ch < NCHUNK; ++ch)
            a += mip[((n0 + i) * NCHUNK + ch) * UU + c];
        xsb[i * XS + c] = (__bf16)a;
    }
#pragma unroll
    for (int p = tid; p < 32 * 128; p += 512) {
        int i = p >> 7, c = p & 127;
        xsb[i * XS + 256 + c] = (__bf16)nf[(n0 + i) * HH + c];
    }
#pragma unroll
    for (int p = tid; p < 32 * 96; p += 512) {
        int i = p / 96, j = p - i * 96;
        float s = 0.f;
#pragma unroll
        for (int ch = 0; ch < NCHUNK; ++ch)
            s += shiftp[((n0 + i) * NCHUNK + ch) * 96 + j];
        out[(n0 + i) * 96 + j] = nv[(n0 + i) * 96 + j] + s * (1.f / 383.f);
    }
    __syncthreads();

    // ---- h1 = silu(xs @ Wh1') ; h2 = silu(h1 @ Wh2') ----
    gemmS<24>(xsb, XS, wh1p, h1b, SS, wave, lane);
    __syncthreads();
    gemmS<16>(h1b, SS, wh2p, h2b, SS, wave, lane);
    __syncthreads();

    // ---- features_out = h2 @ Whl' + nf  (N=128, 16x16 MFMA, 8 n-tiles) ----
    {
        int col = lane & 15, q = lane >> 4;
        int n = wave * 16 + col;
#pragma unroll
        for (int mt = 0; mt < 2; ++mt) {
            f32x4 acc = {0.f, 0.f, 0.f, 0.f};
            const __bf16* xr = h2b + (mt * 16 + col) * SS + q * 8;
#pragma unroll
            for (int kt = 0; kt < 8; ++kt) {
                bf16v8 a = *(const bf16v8*)(xr + kt * 32);
                bf16v8 b = *(const bf16v8*)(whlp + kt * 4096 + n * 32 + q * 8);
                acc = __builtin_amdgcn_mfma_f32_16x16x32_bf16(a, b, acc, 0, 0, 0);
            }
#pragma unroll
            for (int i = 0; i < 4; ++i) {
                int row = n0 + mt * 16 + q * 4 + i;
                out[NN * 96 + row * HH + n] = acc[i] + nf[row * HH + n];
            }
        }
    }
}

// ------------------------------- launcher ----------------------------------
extern "C" void kernel_launch(void* const* d_in, const int* in_sizes, int n_in,
                              void* d_out, int out_size, void* d_ws, size_t ws_size,
                              hipStream_t stream) {
    const float* nv   = (const float*)d_in[0];
    const float* nf   = (const float*)d_in[1];
    const float* We1  = (const float*)d_in[2];
    const float* We2  = (const float*)d_in[3];
    const float* Wx1  = (const float*)d_in[4];
    const float* Wx2  = (const float*)d_in[5];
    const float* Wxl  = (const float*)d_in[6];
    const float* bxl  = (const float*)d_in[7];
    const float* Winf = (const float*)d_in[8];
    const float* Wh1  = (const float*)d_in[9];
    const float* Wh2  = (const float*)d_in[10];
    const float* Whl  = (const float*)d_in[11];
    float* out = (float*)d_out;

    char* ws = (char*)d_ws;
    float*  mip    = (float*)ws;                        // 384*6*256*4 = 2359296
    float*  shiftp = (float*)(ws + 2359296);            // 384*6*96*4  =  884736
    __bf16* we1p   = (__bf16*)(ws + 3244032);           // 147456
    __bf16* we2p   = (__bf16*)(ws + 3391488);           // 131072
    __bf16* wx1p   = (__bf16*)(ws + 3522560);           // 131072
    __bf16* wx2p   = (__bf16*)(ws + 3653632);           // 131072
    __bf16* wh1p   = (__bf16*)(ws + 3784704);           // 196608
    __bf16* wh2p   = (__bf16*)(ws + 3981312);           // 131072
    __bf16* wxlp   = (__bf16*)(ws + 4112384);           // 16384
    __bf16* whlp   = (__bf16*)(ws + 4128768);           // 65536

    repack_all<<<dim3(1856), 256, 0, stream>>>(We1, We2, Wx1, Wx2, Wh1, Wh2, Wxl, Whl,
                                               we1p, we2p, wx1p, wx2p,
                                               wh1p, wh2p, wxlp, whlp);

    edge_kernel<<<dim3(NCHUNK, NN), 512, 0, stream>>>(nv, nf, we1p, we2p, wx1p, wx2p,
                                                      wxlp, bxl, Winf, shiftp, mip);
    node_kernel<<<dim3(12), 512, 0, stream>>>(nv, nf, wh1p, wh2p, whlp,
                                              shiftp, mip, out);
}